// Round 1
// baseline (646.935 us; speedup 1.0000x reference)
//
#include <hip/hip_runtime.h>
#include <hip/hip_bf16.h>
#include <math.h>

#define WAVE 64

__device__ __forceinline__ float wave_reduce_sum(float v) {
    #pragma unroll
    for (int off = 32; off > 0; off >>= 1) v += __shfl_xor(v, off, WAVE);
    return v;
}

// ---------------------------------------------------------------------------
// Kernel: log map (x_hyp (N,129) -> x_tan (N,128)), one wave per node
// ---------------------------------------------------------------------------
__global__ void k_logmap(const float* __restrict__ xh, float* __restrict__ xtan,
                         const float* __restrict__ curv, int N) {
    int wid = (blockIdx.x * blockDim.x + threadIdx.x) >> 6;
    int lane = threadIdx.x & 63;
    if (wid >= N) return;
    float c = fminf(fmaxf(curv[0], 0.1f), 10.f);
    float sqc = sqrtf(c);
    const float* row = xh + (size_t)wid * 129;
    float x0 = row[0];
    float s0 = row[1 + lane];
    float s1 = row[65 + lane];
    float nrm2 = wave_reduce_sum(s0 * s0 + s1 * s1);
    float nrm = fmaxf(sqrtf(nrm2), 1e-6f);
    float x0c = fmaxf(sqc * x0, 1.f + 1e-7f);
    float dist = acoshf(x0c) / sqc;
    float f = dist / nrm;
    float* o = xtan + (size_t)wid * 128;
    o[lane] = s0 * f;
    o[64 + lane] = s1 * f;
}

// ---------------------------------------------------------------------------
// Kernel: build Wt (128 out x 128 in) from w1 (384x64):
//   Wt[o][i] = w1[i][o]        (o <  64)  -> a_dst part
//   Wt[o][i] = w1[128+i][o-64] (o >= 64)  -> a_src part
// ---------------------------------------------------------------------------
__global__ void k_build_wt(const float* __restrict__ w1, float* __restrict__ Wt) {
    int idx = blockIdx.x * 256 + threadIdx.x;   // 0..16383
    int o = idx >> 7, i = idx & 127;
    float v = (o < 64) ? w1[i * 64 + o] : w1[(128 + i) * 64 + (o - 64)];
    Wt[idx] = v;
}

// ---------------------------------------------------------------------------
// Kernel: a_e[t][h] = b1[h] + sum_i emb[t][i] * w1[256+i][h]   (T=4, H=64)
// ---------------------------------------------------------------------------
__global__ void k_prep_ae(const float* __restrict__ emb, const float* __restrict__ w1,
                          const float* __restrict__ b1, float* __restrict__ ae) {
    int tid = threadIdx.x;      // 0..255
    int t = tid >> 6, h = tid & 63;
    float s = b1[h];
    #pragma unroll 8
    for (int i = 0; i < 128; ++i) s += emb[t * 128 + i] * w1[(256 + i) * 64 + h];
    ae[tid] = s;
}

// ---------------------------------------------------------------------------
// GEMM: C[M x 128] = X[M x 128] @ W[128 x 128]^T (+ bias)
//   C[m][o] = sum_k X[m][k] * W[o][k]
// 64x64 tile per block, 256 threads, 4x4 per thread, XOR-swizzled LDS.
// ---------------------------------------------------------------------------
__device__ __forceinline__ int swz(int k, int rq) {
    return k * 64 + ((rq ^ (k & 15)) << 2);
}

__global__ __launch_bounds__(256) void gemm128(
    const float* __restrict__ X, const float* __restrict__ W,
    const float* __restrict__ bias, float* __restrict__ C, int M)
{
    __shared__ float Xs[128 * 64];
    __shared__ float Ws[128 * 64];
    int tid = threadIdx.x;
    int m0 = blockIdx.x * 64;
    int n0 = blockIdx.y * 64;

    // stage X tile (with M guard) and W tile, transposed+swizzled
    for (int s = tid; s < 512; s += 256) {
        int kq = s & 31, rq = s >> 5;
        int kc = kq << 2, r0 = rq << 2;
        float v[4][4];
        #pragma unroll
        for (int i = 0; i < 4; ++i) {
            int row = m0 + r0 + i;
            float4 t;
            if (row < M) t = *(const float4*)&X[(size_t)row * 128 + kc];
            else t = make_float4(0.f, 0.f, 0.f, 0.f);
            v[i][0] = t.x; v[i][1] = t.y; v[i][2] = t.z; v[i][3] = t.w;
        }
        #pragma unroll
        for (int j = 0; j < 4; ++j) {
            int k = kc + j;
            float4 t = make_float4(v[0][j], v[1][j], v[2][j], v[3][j]);
            *(float4*)&Xs[swz(k, rq)] = t;
        }
        #pragma unroll
        for (int i = 0; i < 4; ++i) {
            int row = n0 + r0 + i;   // always < 128
            float4 t = *(const float4*)&W[(size_t)row * 128 + kc];
            v[i][0] = t.x; v[i][1] = t.y; v[i][2] = t.z; v[i][3] = t.w;
        }
        #pragma unroll
        for (int j = 0; j < 4; ++j) {
            int k = kc + j;
            float4 t = make_float4(v[0][j], v[1][j], v[2][j], v[3][j]);
            *(float4*)&Ws[swz(k, rq)] = t;
        }
    }
    __syncthreads();

    int tx = tid & 15, ty = tid >> 4;
    float acc[4][4] = {};
    #pragma unroll 8
    for (int k = 0; k < 128; ++k) {
        float4 a = *(const float4*)&Xs[swz(k, ty)];
        float4 b = *(const float4*)&Ws[swz(k, tx)];
        acc[0][0] += a.x * b.x; acc[0][1] += a.x * b.y; acc[0][2] += a.x * b.z; acc[0][3] += a.x * b.w;
        acc[1][0] += a.y * b.x; acc[1][1] += a.y * b.y; acc[1][2] += a.y * b.z; acc[1][3] += a.y * b.w;
        acc[2][0] += a.z * b.x; acc[2][1] += a.z * b.y; acc[2][2] += a.z * b.z; acc[2][3] += a.z * b.w;
        acc[3][0] += a.w * b.x; acc[3][1] += a.w * b.y; acc[3][2] += a.w * b.z; acc[3][3] += a.w * b.w;
    }

    int r0 = m0 + (ty << 2);
    int c0 = n0 + (tx << 2);
    float4 bb = bias ? *(const float4*)&bias[c0] : make_float4(0.f, 0.f, 0.f, 0.f);
    #pragma unroll
    for (int i = 0; i < 4; ++i) {
        if (r0 + i < M) {
            float4 o = make_float4(acc[i][0] + bb.x, acc[i][1] + bb.y,
                                   acc[i][2] + bb.z, acc[i][3] + bb.w);
            *(float4*)&C[(size_t)(r0 + i) * 128 + c0] = o;
        }
    }
}

// ---------------------------------------------------------------------------
// Edge pass A: one wave per edge.
//   pre[h] = a_cat[dst][h] + a_cat[src][64+h] + ae[t][h]
//   score  = sum_h silu(pre[h]) * w2[h] + b2 + log(clip(ew)) + (t==1)*sib
//   ex[e]  = exp(score);  seg_sum[dst] += ex
// ---------------------------------------------------------------------------
__global__ void k_passA(const int* __restrict__ ei, const int* __restrict__ et,
                        const float* __restrict__ ew, const float* __restrict__ acat,
                        const float* __restrict__ ae, const float* __restrict__ w2,
                        const float* __restrict__ b2, const float* __restrict__ sib,
                        float* __restrict__ exb, float* __restrict__ segs, int E)
{
    int e = (blockIdx.x * blockDim.x + threadIdx.x) >> 6;
    int lane = threadIdx.x & 63;
    if (e >= E) return;
    int src = ei[e];
    int dst = ei[E + e];
    int t = et[e];
    float w = ew[e];
    float pre = acat[(size_t)dst * 128 + lane] + acat[(size_t)src * 128 + 64 + lane]
              + ae[t * 64 + lane];
    float h = pre / (1.f + expf(-pre));       // silu
    float s = wave_reduce_sum(h * w2[lane]);
    if (lane == 0) {
        s += b2[0] + logf(fmaxf(w, 1e-6f));
        if (t == 1) s += sib[0];
        float exv = expf(s);
        exb[e] = exv;
        atomicAdd(&segs[dst], exv);
    }
}

// ---------------------------------------------------------------------------
// Edge pass B: one wave per edge, scatter message into x_agg via atomics.
//   coeff = ex[e] / (seg_sum[dst]+1e-16) * ew
//   x_agg[dst][d] += (x_lin[src][d] + emb[t][d]) * coeff
// ---------------------------------------------------------------------------
__global__ void k_passB(const int* __restrict__ ei, const int* __restrict__ et,
                        const float* __restrict__ ew, const float* __restrict__ xlin,
                        const float* __restrict__ emb, const float* __restrict__ exb,
                        const float* __restrict__ segs, float* __restrict__ xagg, int E)
{
    int e = (blockIdx.x * blockDim.x + threadIdx.x) >> 6;
    int lane = threadIdx.x & 63;
    if (e >= E) return;
    int src = ei[e];
    int dst = ei[E + e];
    int t = et[e];
    float w = ew[e];
    float coeff = exb[e] / (segs[dst] + 1e-16f) * w;
    float v0 = (xlin[(size_t)src * 128 + lane]      + emb[t * 128 + lane])      * coeff;
    float v1 = (xlin[(size_t)src * 128 + 64 + lane] + emb[t * 128 + 64 + lane]) * coeff;
    atomicAdd(&xagg[(size_t)dst * 128 + lane], v0);
    atomicAdd(&xagg[(size_t)dst * 128 + 64 + lane], v1);
}

// ---------------------------------------------------------------------------
// LN + exp map: x_out = LN(x_tan + x_agg)*g+b; out = exp_map(x_out)
// one wave per node
// ---------------------------------------------------------------------------
__global__ void k_ln_exp(const float* __restrict__ xtan, const float* __restrict__ xagg,
                         const float* __restrict__ g, const float* __restrict__ b,
                         const float* __restrict__ curv, float* __restrict__ out, int N)
{
    int wid = (blockIdx.x * blockDim.x + threadIdx.x) >> 6;
    int lane = threadIdx.x & 63;
    if (wid >= N) return;
    float c = fminf(fmaxf(curv[0], 0.1f), 10.f);
    float sqc = sqrtf(c);
    size_t base = (size_t)wid * 128;
    float y0 = xtan[base + lane]      + xagg[base + lane];
    float y1 = xtan[base + 64 + lane] + xagg[base + 64 + lane];
    float sum = wave_reduce_sum(y0 + y1);
    float mu = sum * (1.f / 128.f);
    float sq = wave_reduce_sum(y0 * y0 + y1 * y1);
    float var = sq * (1.f / 128.f) - mu * mu;
    float inv = rsqrtf(var + 1e-5f);
    y0 = (y0 - mu) * inv * g[lane]      + b[lane];
    y1 = (y1 - mu) * inv * g[64 + lane] + b[64 + lane];
    float nrm2 = wave_reduce_sum(y0 * y0 + y1 * y1);
    float nrm = fmaxf(sqrtf(nrm2), 1e-6f);
    float th = sqc * nrm;
    float sc = sinhf(th) / (sqc * nrm);
    float* o = out + (size_t)wid * 129;
    if (lane == 0) o[0] = coshf(th) / sqc;
    o[1 + lane] = y0 * sc;
    o[65 + lane] = y1 * sc;
}

// ---------------------------------------------------------------------------
extern "C" void kernel_launch(void* const* d_in, const int* in_sizes, int n_in,
                              void* d_out, int out_size, void* d_ws, size_t ws_size,
                              hipStream_t stream) {
    const float* x_hyp = (const float*)d_in[0];
    const int*   ei    = (const int*)d_in[1];
    const int*   et    = (const int*)d_in[2];
    const float* ew    = (const float*)d_in[3];
    const float* lin_w = (const float*)d_in[4];
    const float* lin_b = (const float*)d_in[5];
    const float* ln_g  = (const float*)d_in[6];
    const float* ln_b  = (const float*)d_in[7];
    const float* emb   = (const float*)d_in[8];
    const float* w1    = (const float*)d_in[9];
    const float* b1    = (const float*)d_in[10];
    const float* w2    = (const float*)d_in[11];
    const float* b2    = (const float*)d_in[12];
    const float* sib   = (const float*)d_in[13];
    const float* curv  = (const float*)d_in[14];
    float* out = (float*)d_out;
    float* ws  = (float*)d_ws;

    const int N = in_sizes[0] / 129;
    const int E = in_sizes[2];
    const int L = in_sizes[4] / (128 * 128);

    float* xtan = ws;                          // N*128
    float* xlin = xtan + (size_t)N * 128;      // N*128
    float* acat = xlin + (size_t)N * 128;      // N*128  (reused as x_agg)
    float* exb  = acat + (size_t)N * 128;      // E
    float* segs = exb + E;                     // N
    float* Wt   = segs + N;                    // 128*128
    float* ae   = Wt + 128 * 128;              // 4*64

    const float* xin = x_hyp;
    for (int l = 0; l < L; ++l) {
        const float* w1l = w1 + (size_t)l * 384 * 64;
        k_logmap<<<(N + 3) / 4, 256, 0, stream>>>(xin, xtan, curv + l, N);
        k_build_wt<<<64, 256, 0, stream>>>(w1l, Wt);
        k_prep_ae<<<1, 256, 0, stream>>>(emb + (size_t)l * 512, w1l, b1 + (size_t)l * 64, ae);
        gemm128<<<dim3((N + 63) / 64, 2), 256, 0, stream>>>(
            xtan, lin_w + (size_t)l * 128 * 128, lin_b + (size_t)l * 128, xlin, N);
        gemm128<<<dim3((N + 63) / 64, 2), 256, 0, stream>>>(
            xlin, Wt, nullptr, acat, N);
        hipMemsetAsync(segs, 0, (size_t)N * sizeof(float), stream);
        k_passA<<<(E + 3) / 4, 256, 0, stream>>>(ei, et, ew, acat, ae,
            w2 + (size_t)l * 64, b2 + l, sib + l, exb, segs, E);
        hipMemsetAsync(acat, 0, (size_t)N * 128 * sizeof(float), stream);
        k_passB<<<(E + 3) / 4, 256, 0, stream>>>(ei, et, ew, xlin,
            emb + (size_t)l * 512, exb, segs, acat, E);
        k_ln_exp<<<(N + 3) / 4, 256, 0, stream>>>(xtan, acat,
            ln_g + (size_t)l * 128, ln_b + (size_t)l * 128, curv + l, out, N);
        xin = out;
    }
}

// Round 2
// 458.654 us; speedup vs baseline: 1.4105x; 1.4105x over previous
//
#include <hip/hip_runtime.h>
#include <hip/hip_bf16.h>
#include <math.h>

#define WAVE 64

__device__ __forceinline__ float wave_reduce_sum(float v) {
    #pragma unroll
    for (int off = 32; off > 0; off >>= 1) v += __shfl_xor(v, off, WAVE);
    return v;
}

// ---------------------------------------------------------------------------
// log map (x_hyp (N,129) -> x_tan (N,128)), one wave per node
// ---------------------------------------------------------------------------
__global__ void k_logmap(const float* __restrict__ xh, float* __restrict__ xtan,
                         const float* __restrict__ curv, int N) {
    int wid = (blockIdx.x * blockDim.x + threadIdx.x) >> 6;
    int lane = threadIdx.x & 63;
    if (wid >= N) return;
    float c = fminf(fmaxf(curv[0], 0.1f), 10.f);
    float sqc = sqrtf(c);
    const float* row = xh + (size_t)wid * 129;
    float x0 = row[0];
    float s0 = row[1 + lane];
    float s1 = row[65 + lane];
    float nrm2 = wave_reduce_sum(s0 * s0 + s1 * s1);
    float nrm = fmaxf(sqrtf(nrm2), 1e-6f);
    float x0c = fmaxf(sqc * x0, 1.f + 1e-7f);
    float dist = acoshf(x0c) / sqc;
    float f = dist / nrm;
    float* o = xtan + (size_t)wid * 128;
    o[lane] = s0 * f;
    o[64 + lane] = s1 * f;
}

// ---------------------------------------------------------------------------
// Wt (128x128) from w1 (384x64): Wt[o][i] = o<64 ? w1[i][o] : w1[128+i][o-64]
// ---------------------------------------------------------------------------
__global__ void k_build_wt(const float* __restrict__ w1, float* __restrict__ Wt) {
    int idx = blockIdx.x * 256 + threadIdx.x;
    int o = idx >> 7, i = idx & 127;
    Wt[idx] = (o < 64) ? w1[i * 64 + o] : w1[(128 + i) * 64 + (o - 64)];
}

// ---------------------------------------------------------------------------
// a_e[t][h] = b1[h] + sum_i emb[t][i] * w1[256+i][h]   (T=4, H=64)
// ---------------------------------------------------------------------------
__global__ void k_prep_ae(const float* __restrict__ emb, const float* __restrict__ w1,
                          const float* __restrict__ b1, float* __restrict__ ae) {
    int tid = threadIdx.x;
    int t = tid >> 6, h = tid & 63;
    float s = b1[h];
    #pragma unroll 8
    for (int i = 0; i < 128; ++i) s += emb[t * 128 + i] * w1[(256 + i) * 64 + h];
    ae[tid] = s;
}

// ---------------------------------------------------------------------------
// CSR build: histogram -> hierarchical exclusive scan -> scatter packed edges
// epack[p] = { src | (t<<24), float_bits(w) }
// ---------------------------------------------------------------------------
__global__ void k_hist(const int* __restrict__ ei, int* __restrict__ deg, int E) {
    int e = blockIdx.x * 256 + threadIdx.x;
    if (e < E) atomicAdd(&deg[ei[E + e]], 1);
}

// per 256-block: exclusive scan within block -> rs, block total -> btot
__global__ void k_scan1(const int* __restrict__ deg, int* __restrict__ rs,
                        int* __restrict__ btot, int N) {
    __shared__ int wsum[4];
    int i = blockIdx.x * 256 + threadIdx.x;
    int v = (i < N) ? deg[i] : 0;
    int lane = threadIdx.x & 63, w = threadIdx.x >> 6;
    int x = v;
    #pragma unroll
    for (int off = 1; off < 64; off <<= 1) {
        int t = __shfl_up(x, off, 64);
        if (lane >= off) x += t;
    }
    if (lane == 63) wsum[w] = x;
    __syncthreads();
    int woff = 0;
    for (int j = 0; j < w; ++j) woff += wsum[j];
    int incl = woff + x;
    if (i < N) rs[i] = incl - v;
    if (threadIdx.x == 255) btot[blockIdx.x] = incl;
}

// single block: exclusive scan of nb block totals in place
__global__ void k_scan2(int* __restrict__ btot, int nb) {
    __shared__ int wsum[4];
    int i = threadIdx.x;
    int v = (i < nb) ? btot[i] : 0;
    int lane = i & 63, w = i >> 6;
    int x = v;
    #pragma unroll
    for (int off = 1; off < 64; off <<= 1) {
        int t = __shfl_up(x, off, 64);
        if (lane >= off) x += t;
    }
    if (lane == 63) wsum[w] = x;
    __syncthreads();
    int woff = 0;
    for (int j = 0; j < w; ++j) woff += wsum[j];
    int incl = woff + x;
    __syncthreads();
    if (i < nb) btot[i] = incl - v;
}

__global__ void k_scan3(int* __restrict__ rs, const int* __restrict__ btot,
                        int* __restrict__ cursor, int N, int E) {
    int i = blockIdx.x * 256 + threadIdx.x;
    if (i < N) {
        int v = rs[i] + btot[blockIdx.x];
        rs[i] = v;
        cursor[i] = v;
    }
    if (i == 0) rs[N] = E;
}

__global__ void k_scatter(const int* __restrict__ ei, const int* __restrict__ et,
                          const float* __restrict__ ew, int* __restrict__ cursor,
                          int2* __restrict__ epack, int E) {
    int e = blockIdx.x * 256 + threadIdx.x;
    if (e >= E) return;
    int dst = ei[E + e];
    int pos = atomicAdd(&cursor[dst], 1);
    int2 r;
    r.x = ei[e] | (et[e] << 24);
    r.y = __float_as_int(ew[e]);
    epack[pos] = r;
}

// ---------------------------------------------------------------------------
// GEMM: C[M x 128] = X[M x 128] @ W[128 x 128]^T (+ bias)
// 64x64 tile per block, 256 threads, 4x4 per thread, XOR-swizzled LDS.
// ---------------------------------------------------------------------------
__device__ __forceinline__ int swz(int k, int rq) {
    return k * 64 + ((rq ^ (k & 15)) << 2);
}

__global__ __launch_bounds__(256) void gemm128(
    const float* __restrict__ X, const float* __restrict__ W,
    const float* __restrict__ bias, float* __restrict__ C, int M)
{
    __shared__ float Xs[128 * 64];
    __shared__ float Ws[128 * 64];
    int tid = threadIdx.x;
    int m0 = blockIdx.x * 64;
    int n0 = blockIdx.y * 64;

    for (int s = tid; s < 512; s += 256) {
        int kq = s & 31, rq = s >> 5;
        int kc = kq << 2, r0 = rq << 2;
        float v[4][4];
        #pragma unroll
        for (int i = 0; i < 4; ++i) {
            int row = m0 + r0 + i;
            float4 t;
            if (row < M) t = *(const float4*)&X[(size_t)row * 128 + kc];
            else t = make_float4(0.f, 0.f, 0.f, 0.f);
            v[i][0] = t.x; v[i][1] = t.y; v[i][2] = t.z; v[i][3] = t.w;
        }
        #pragma unroll
        for (int j = 0; j < 4; ++j) {
            int k = kc + j;
            *(float4*)&Xs[swz(k, rq)] = make_float4(v[0][j], v[1][j], v[2][j], v[3][j]);
        }
        #pragma unroll
        for (int i = 0; i < 4; ++i) {
            int row = n0 + r0 + i;
            float4 t = *(const float4*)&W[(size_t)row * 128 + kc];
            v[i][0] = t.x; v[i][1] = t.y; v[i][2] = t.z; v[i][3] = t.w;
        }
        #pragma unroll
        for (int j = 0; j < 4; ++j) {
            int k = kc + j;
            *(float4*)&Ws[swz(k, rq)] = make_float4(v[0][j], v[1][j], v[2][j], v[3][j]);
        }
    }
    __syncthreads();

    int tx = tid & 15, ty = tid >> 4;
    float acc[4][4] = {};
    #pragma unroll 8
    for (int k = 0; k < 128; ++k) {
        float4 a = *(const float4*)&Xs[swz(k, ty)];
        float4 b = *(const float4*)&Ws[swz(k, tx)];
        acc[0][0] += a.x * b.x; acc[0][1] += a.x * b.y; acc[0][2] += a.x * b.z; acc[0][3] += a.x * b.w;
        acc[1][0] += a.y * b.x; acc[1][1] += a.y * b.y; acc[1][2] += a.y * b.z; acc[1][3] += a.y * b.w;
        acc[2][0] += a.z * b.x; acc[2][1] += a.z * b.y; acc[2][2] += a.z * b.z; acc[2][3] += a.z * b.w;
        acc[3][0] += a.w * b.x; acc[3][1] += a.w * b.y; acc[3][2] += a.w * b.z; acc[3][3] += a.w * b.w;
    }

    int r0 = m0 + (ty << 2);
    int c0 = n0 + (tx << 2);
    float4 bb = bias ? *(const float4*)&bias[c0] : make_float4(0.f, 0.f, 0.f, 0.f);
    #pragma unroll
    for (int i = 0; i < 4; ++i) {
        if (r0 + i < M) {
            *(float4*)&C[(size_t)(r0 + i) * 128 + c0] =
                make_float4(acc[i][0] + bb.x, acc[i][1] + bb.y,
                            acc[i][2] + bb.z, acc[i][3] + bb.w);
        }
    }
}

// ---------------------------------------------------------------------------
// Fused per-dst aggregation: one wave per node.
//   For each edge (src,t,w) of node n:
//     pre[h] = a_dst[n][h] + a_src[src][h] + ae[t][h]
//     s = sum_h silu(pre)*w2 + b2 + log(w) + (t==1)*sib ; ex = exp(s)
//     S += ex ; acc += (xlin[src] + emb[t]) * (ex*w)
//   y = xtan[n] + acc/(S+1e-16); LayerNorm; exp-map; write out row (129)
// ---------------------------------------------------------------------------
__global__ __launch_bounds__(256) void k_aggregate(
    const int* __restrict__ rs, const int2* __restrict__ epack,
    const float* __restrict__ acat, const float* __restrict__ xlin,
    const float* __restrict__ xtan, const float* __restrict__ ae,
    const float* __restrict__ emb, const float* __restrict__ w2,
    const float* __restrict__ b2, const float* __restrict__ sib,
    const float* __restrict__ g, const float* __restrict__ b,
    const float* __restrict__ curv, float* __restrict__ out, int N)
{
    int wid = (blockIdx.x * blockDim.x + threadIdx.x) >> 6;
    int lane = threadIdx.x & 63;
    if (wid >= N) return;
    float c = fminf(fmaxf(curv[0], 0.1f), 10.f);
    float sqc = sqrtf(c);
    float b2v = b2[0], sibv = sib[0];
    float w2l = w2[lane];
    int p0 = rs[wid], p1 = rs[wid + 1];
    size_t base = (size_t)wid * 128;
    float a_dst = acat[base + lane];

    float acc0 = 0.f, acc1 = 0.f, S = 0.f;
    for (int p = p0; p < p1; ++p) {
        int2 r = epack[p];
        int src = r.x & 0xFFFFFF;
        int t = ((unsigned)r.x) >> 24;
        float w = __int_as_float(r.y);
        float pre = a_dst + acat[(size_t)src * 128 + 64 + lane] + ae[t * 64 + lane];
        float h = pre / (1.f + expf(-pre));           // silu
        float s = wave_reduce_sum(h * w2l);
        s += b2v + logf(fmaxf(w, 1e-6f));
        if (t == 1) s += sibv;
        float ex = expf(s);                            // bounded, no max needed
        S += ex;
        float cf = ex * w;
        acc0 += (xlin[(size_t)src * 128 + lane]      + emb[t * 128 + lane])      * cf;
        acc1 += (xlin[(size_t)src * 128 + 64 + lane] + emb[t * 128 + 64 + lane]) * cf;
    }
    float inv = 1.f / (S + 1e-16f);
    float y0 = xtan[base + lane]      + acc0 * inv;
    float y1 = xtan[base + 64 + lane] + acc1 * inv;

    // LayerNorm
    float mu = wave_reduce_sum(y0 + y1) * (1.f / 128.f);
    float sq = wave_reduce_sum(y0 * y0 + y1 * y1);
    float var = sq * (1.f / 128.f) - mu * mu;
    float invs = rsqrtf(var + 1e-5f);
    y0 = (y0 - mu) * invs * g[lane]      + b[lane];
    y1 = (y1 - mu) * invs * g[64 + lane] + b[64 + lane];

    // exp map
    float nrm2 = wave_reduce_sum(y0 * y0 + y1 * y1);
    float nrm = fmaxf(sqrtf(nrm2), 1e-6f);
    float th = sqc * nrm;
    float sc = sinhf(th) / (sqc * nrm);
    float* o = out + (size_t)wid * 129;
    if (lane == 0) o[0] = coshf(th) / sqc;
    o[1 + lane]  = y0 * sc;
    o[65 + lane] = y1 * sc;
}

// ---------------------------------------------------------------------------
extern "C" void kernel_launch(void* const* d_in, const int* in_sizes, int n_in,
                              void* d_out, int out_size, void* d_ws, size_t ws_size,
                              hipStream_t stream) {
    const float* x_hyp = (const float*)d_in[0];
    const int*   ei    = (const int*)d_in[1];
    const int*   et    = (const int*)d_in[2];
    const float* ew    = (const float*)d_in[3];
    const float* lin_w = (const float*)d_in[4];
    const float* lin_b = (const float*)d_in[5];
    const float* ln_g  = (const float*)d_in[6];
    const float* ln_b  = (const float*)d_in[7];
    const float* emb   = (const float*)d_in[8];
    const float* w1    = (const float*)d_in[9];
    const float* b1    = (const float*)d_in[10];
    const float* w2    = (const float*)d_in[11];
    const float* b2    = (const float*)d_in[12];
    const float* sib   = (const float*)d_in[13];
    const float* curv  = (const float*)d_in[14];
    float* out = (float*)d_out;
    float* ws  = (float*)d_ws;

    const int N = in_sizes[0] / 129;
    const int E = in_sizes[2];
    const int L = in_sizes[4] / (128 * 128);
    const int NB = (N + 255) / 256;   // scan blocks (<=256 assumed: N<=65536)

    // float region
    float* xtan = ws;                               // N*128
    float* xlin = xtan + (size_t)N * 128;           // N*128
    float* acat = xlin + (size_t)N * 128;           // N*128
    // int region (starts 16B-aligned: 3*N*128*4 bytes, N mult of 8 -> ok)
    int2* epack = (int2*)(acat + (size_t)N * 128);  // E int2
    int* deg    = (int*)(epack + E);                // N   (reused as cursor)
    int* rs     = deg + N;                          // N+1
    int* btot   = rs + N + 1;                       // 256
    float* Wt   = (float*)(btot + 256);             // 128*128
    float* ae   = Wt + 128 * 128;                   // 256

    // ---- CSR build (once; edges static across layers) ----
    hipMemsetAsync(deg, 0, (size_t)N * sizeof(int), stream);
    k_hist<<<(E + 255) / 256, 256, 0, stream>>>(ei, deg, E);
    k_scan1<<<NB, 256, 0, stream>>>(deg, rs, btot, N);
    k_scan2<<<1, 256, 0, stream>>>(btot, NB);
    k_scan3<<<NB, 256, 0, stream>>>(rs, btot, deg /*cursor*/, N, E);
    k_scatter<<<(E + 255) / 256, 256, 0, stream>>>(ei, et, ew, deg /*cursor*/, epack, E);

    const float* xin = x_hyp;
    for (int l = 0; l < L; ++l) {
        const float* w1l = w1 + (size_t)l * 384 * 64;
        const float* embl = emb + (size_t)l * 4 * 128;
        k_logmap<<<(N + 3) / 4, 256, 0, stream>>>(xin, xtan, curv + l, N);
        k_build_wt<<<64, 256, 0, stream>>>(w1l, Wt);
        k_prep_ae<<<1, 256, 0, stream>>>(embl, w1l, b1 + (size_t)l * 64, ae);
        gemm128<<<dim3((N + 63) / 64, 2), 256, 0, stream>>>(
            xtan, lin_w + (size_t)l * 128 * 128, lin_b + (size_t)l * 128, xlin, N);
        gemm128<<<dim3((N + 63) / 64, 2), 256, 0, stream>>>(
            xlin, Wt, nullptr, acat, N);
        k_aggregate<<<(N + 3) / 4, 256, 0, stream>>>(
            rs, epack, acat, xlin, xtan, ae, embl,
            w2 + (size_t)l * 64, b2 + l, sib + l,
            ln_g + (size_t)l * 128, ln_b + (size_t)l * 128, curv + l, out, N);
        xin = out;
    }
}

// Round 3
// 445.525 us; speedup vs baseline: 1.4521x; 1.0295x over previous
//
#include <hip/hip_runtime.h>
#include <hip/hip_bf16.h>
#include <math.h>

#define WAVE 64

__device__ __forceinline__ float wave_reduce_sum(float v) {
    #pragma unroll
    for (int off = 32; off > 0; off >>= 1) v += __shfl_xor(v, off, WAVE);
    return v;
}

// ---------------------------------------------------------------------------
// log map (x_hyp (N,129) -> x_tan (N,128)), one wave per node
// ---------------------------------------------------------------------------
__global__ void k_logmap(const float* __restrict__ xh, float* __restrict__ xtan,
                         const float* __restrict__ curv, int N) {
    int wid = (blockIdx.x * blockDim.x + threadIdx.x) >> 6;
    int lane = threadIdx.x & 63;
    if (wid >= N) return;
    float c = fminf(fmaxf(curv[0], 0.1f), 10.f);
    float sqc = sqrtf(c);
    const float* row = xh + (size_t)wid * 129;
    float x0 = row[0];
    float s0 = row[1 + lane];
    float s1 = row[65 + lane];
    float nrm2 = wave_reduce_sum(s0 * s0 + s1 * s1);
    float nrm = fmaxf(sqrtf(nrm2), 1e-6f);
    float x0c = fmaxf(sqc * x0, 1.f + 1e-7f);
    float dist = acoshf(x0c) / sqc;
    float f = dist / nrm;
    float* o = xtan + (size_t)wid * 128;
    o[lane] = s0 * f;
    o[64 + lane] = s1 * f;
}

// ---------------------------------------------------------------------------
// Wt (128x128) from w1 (384x64): Wt[o][i] = o<64 ? w1[i][o] : w1[128+i][o-64]
// ---------------------------------------------------------------------------
__global__ void k_build_wt(const float* __restrict__ w1, float* __restrict__ Wt) {
    int idx = blockIdx.x * 256 + threadIdx.x;
    int o = idx >> 7, i = idx & 127;
    Wt[idx] = (o < 64) ? w1[i * 64 + o] : w1[(128 + i) * 64 + (o - 64)];
}

// ---------------------------------------------------------------------------
// a_e[t][h] = b1[h] + sum_i emb[t][i] * w1[256+i][h]   (T=4, H=64)
// ---------------------------------------------------------------------------
__global__ void k_prep_ae(const float* __restrict__ emb, const float* __restrict__ w1,
                          const float* __restrict__ b1, float* __restrict__ ae) {
    int tid = threadIdx.x;
    int t = tid >> 6, h = tid & 63;
    float s = b1[h];
    #pragma unroll 8
    for (int i = 0; i < 128; ++i) s += emb[t * 128 + i] * w1[(256 + i) * 64 + h];
    ae[tid] = s;
}

// ---------------------------------------------------------------------------
// CSR build: histogram -> hierarchical exclusive scan -> scatter packed edges
// epack[p] = { src | (t<<24), float_bits(w) }, edst[p] = dst
// ---------------------------------------------------------------------------
__global__ void k_hist(const int* __restrict__ ei, int* __restrict__ deg, int E) {
    int e = blockIdx.x * 256 + threadIdx.x;
    if (e < E) atomicAdd(&deg[ei[E + e]], 1);
}

__global__ void k_scan1(const int* __restrict__ deg, int* __restrict__ rs,
                        int* __restrict__ btot, int N) {
    __shared__ int wsum[4];
    int i = blockIdx.x * 256 + threadIdx.x;
    int v = (i < N) ? deg[i] : 0;
    int lane = threadIdx.x & 63, w = threadIdx.x >> 6;
    int x = v;
    #pragma unroll
    for (int off = 1; off < 64; off <<= 1) {
        int t = __shfl_up(x, off, 64);
        if (lane >= off) x += t;
    }
    if (lane == 63) wsum[w] = x;
    __syncthreads();
    int woff = 0;
    for (int j = 0; j < w; ++j) woff += wsum[j];
    int incl = woff + x;
    if (i < N) rs[i] = incl - v;
    if (threadIdx.x == 255) btot[blockIdx.x] = incl;
}

__global__ void k_scan2(int* __restrict__ btot, int nb) {
    __shared__ int wsum[4];
    int i = threadIdx.x;
    int v = (i < nb) ? btot[i] : 0;
    int lane = i & 63, w = i >> 6;
    int x = v;
    #pragma unroll
    for (int off = 1; off < 64; off <<= 1) {
        int t = __shfl_up(x, off, 64);
        if (lane >= off) x += t;
    }
    if (lane == 63) wsum[w] = x;
    __syncthreads();
    int woff = 0;
    for (int j = 0; j < w; ++j) woff += wsum[j];
    int incl = woff + x;
    __syncthreads();
    if (i < nb) btot[i] = incl - v;
}

__global__ void k_scan3(int* __restrict__ rs, const int* __restrict__ btot,
                        int* __restrict__ cursor, int N, int E) {
    int i = blockIdx.x * 256 + threadIdx.x;
    if (i < N) {
        int v = rs[i] + btot[blockIdx.x];
        rs[i] = v;
        cursor[i] = v;
    }
    if (i == 0) rs[N] = E;
}

__global__ void k_scatter(const int* __restrict__ ei, const int* __restrict__ et,
                          const float* __restrict__ ew, int* __restrict__ cursor,
                          int2* __restrict__ epack, int* __restrict__ edst, int E) {
    int e = blockIdx.x * 256 + threadIdx.x;
    if (e >= E) return;
    int dst = ei[E + e];
    int pos = atomicAdd(&cursor[dst], 1);
    int2 r;
    r.x = ei[e] | (et[e] << 24);
    r.y = __float_as_int(ew[e]);
    epack[pos] = r;
    edst[pos] = dst;
}

// ---------------------------------------------------------------------------
// GEMM: C[M x 128] = X[M x 128] @ W[128 x 128]^T (+ bias)
// 64x64 tile per block, 256 threads, 4x4 per thread, XOR-swizzled LDS.
// ---------------------------------------------------------------------------
__device__ __forceinline__ int swz(int k, int rq) {
    return k * 64 + ((rq ^ (k & 15)) << 2);
}

__global__ __launch_bounds__(256) void gemm128(
    const float* __restrict__ X, const float* __restrict__ W,
    const float* __restrict__ bias, float* __restrict__ C, int M)
{
    __shared__ float Xs[128 * 64];
    __shared__ float Ws[128 * 64];
    int tid = threadIdx.x;
    int m0 = blockIdx.x * 64;
    int n0 = blockIdx.y * 64;

    for (int s = tid; s < 512; s += 256) {
        int kq = s & 31, rq = s >> 5;
        int kc = kq << 2, r0 = rq << 2;
        float v[4][4];
        #pragma unroll
        for (int i = 0; i < 4; ++i) {
            int row = m0 + r0 + i;
            float4 t;
            if (row < M) t = *(const float4*)&X[(size_t)row * 128 + kc];
            else t = make_float4(0.f, 0.f, 0.f, 0.f);
            v[i][0] = t.x; v[i][1] = t.y; v[i][2] = t.z; v[i][3] = t.w;
        }
        #pragma unroll
        for (int j = 0; j < 4; ++j) {
            int k = kc + j;
            *(float4*)&Xs[swz(k, rq)] = make_float4(v[0][j], v[1][j], v[2][j], v[3][j]);
        }
        #pragma unroll
        for (int i = 0; i < 4; ++i) {
            int row = n0 + r0 + i;
            float4 t = *(const float4*)&W[(size_t)row * 128 + kc];
            v[i][0] = t.x; v[i][1] = t.y; v[i][2] = t.z; v[i][3] = t.w;
        }
        #pragma unroll
        for (int j = 0; j < 4; ++j) {
            int k = kc + j;
            *(float4*)&Ws[swz(k, rq)] = make_float4(v[0][j], v[1][j], v[2][j], v[3][j]);
        }
    }
    __syncthreads();

    int tx = tid & 15, ty = tid >> 4;
    float acc[4][4] = {};
    #pragma unroll 8
    for (int k = 0; k < 128; ++k) {
        float4 a = *(const float4*)&Xs[swz(k, ty)];
        float4 b = *(const float4*)&Ws[swz(k, tx)];
        acc[0][0] += a.x * b.x; acc[0][1] += a.x * b.y; acc[0][2] += a.x * b.z; acc[0][3] += a.x * b.w;
        acc[1][0] += a.y * b.x; acc[1][1] += a.y * b.y; acc[1][2] += a.y * b.z; acc[1][3] += a.y * b.w;
        acc[2][0] += a.z * b.x; acc[2][1] += a.z * b.y; acc[2][2] += a.z * b.z; acc[2][3] += a.z * b.w;
        acc[3][0] += a.w * b.x; acc[3][1] += a.w * b.y; acc[3][2] += a.w * b.z; acc[3][3] += a.w * b.w;
    }

    int r0 = m0 + (ty << 2);
    int c0 = n0 + (tx << 2);
    float4 bb = bias ? *(const float4*)&bias[c0] : make_float4(0.f, 0.f, 0.f, 0.f);
    #pragma unroll
    for (int i = 0; i < 4; ++i) {
        if (r0 + i < M) {
            *(float4*)&C[(size_t)(r0 + i) * 128 + c0] =
                make_float4(acc[i][0] + bb.x, acc[i][1] + bb.y,
                            acc[i][2] + bb.z, acc[i][3] + bb.w);
        }
    }
}

// ---------------------------------------------------------------------------
// Per-edge score: 16 lanes per edge (4 edges/wave), CSR edge order.
//   pre[h] = a_dst[dst][h] + a_src[src][h] + ae[t][h]   (h = 4*li .. 4*li+3)
//   s = sum_h silu(pre)*w2 + b2 + log(w) + (t==1)*sib ;  exb[p] = exp(s)
// ---------------------------------------------------------------------------
__device__ __forceinline__ float silu(float x) { return x / (1.f + expf(-x)); }

__global__ __launch_bounds__(256) void k_score(
    const int2* __restrict__ epack, const int* __restrict__ edst,
    const float* __restrict__ acat, const float* __restrict__ ae,
    const float* __restrict__ w2, const float* __restrict__ b2,
    const float* __restrict__ sib, float* __restrict__ exb, int E)
{
    int gid = blockIdx.x * 256 + threadIdx.x;
    int e = gid >> 4;
    int li = threadIdx.x & 15;
    if (e >= E) return;
    int2 r = epack[e];
    int src = r.x & 0xFFFFFF;
    int t = ((unsigned)r.x) >> 24;
    float w = __int_as_float(r.y);
    int dst = edst[e];

    float4 ad = *(const float4*)&acat[(size_t)dst * 128 + 4 * li];
    float4 as = *(const float4*)&acat[(size_t)src * 128 + 64 + 4 * li];
    float4 av = *(const float4*)&ae[t * 64 + 4 * li];
    float4 wv = *(const float4*)&w2[4 * li];
    float d = silu(ad.x + as.x + av.x) * wv.x
            + silu(ad.y + as.y + av.y) * wv.y
            + silu(ad.z + as.z + av.z) * wv.z
            + silu(ad.w + as.w + av.w) * wv.w;
    #pragma unroll
    for (int m = 1; m < 16; m <<= 1) d += __shfl_xor(d, m, WAVE);
    if (li == 0) {
        float s = d + b2[0] + logf(fmaxf(w, 1e-6f));
        if (t == 1) s += sib[0];
        exb[e] = expf(s);
    }
}

// ---------------------------------------------------------------------------
// Per-node gather: one wave per node, 2 edges/iter via 32-lane halves.
//   acc[d] += (xlin[src][d] + emb[t][d]) * ex*w ;  S += ex
//   y = xtan + acc/(S+1e-16) ; LayerNorm ; exp-map ; write out row (129)
// ---------------------------------------------------------------------------
__global__ __launch_bounds__(256) void k_gather(
    const int* __restrict__ rs, const int2* __restrict__ epack,
    const float* __restrict__ exb, const float* __restrict__ xlin,
    const float* __restrict__ xtan, const float* __restrict__ emb,
    const float* __restrict__ g, const float* __restrict__ b,
    const float* __restrict__ curv, float* __restrict__ out, int N)
{
    int wid = (blockIdx.x * blockDim.x + threadIdx.x) >> 6;
    int lane = threadIdx.x & 63;
    if (wid >= N) return;
    int half = lane >> 5;      // which edge of the pair
    int li = lane & 31;        // covers dims 4*li .. 4*li+3
    float c = fminf(fmaxf(curv[0], 0.1f), 10.f);
    float sqc = sqrtf(c);
    int p0 = rs[wid], p1 = rs[wid + 1];

    float4 acc = make_float4(0.f, 0.f, 0.f, 0.f);
    float S = 0.f;
    for (int p = p0 + half; p < p1; p += 2) {
        int2 r = epack[p];
        int src = r.x & 0xFFFFFF;
        int t = ((unsigned)r.x) >> 24;
        float w = __int_as_float(r.y);
        float ex = exb[p];
        float cf = ex * w;
        float4 xs = *(const float4*)&xlin[(size_t)src * 128 + 4 * li];
        float4 em = *(const float4*)&emb[t * 128 + 4 * li];
        acc.x += (xs.x + em.x) * cf;
        acc.y += (xs.y + em.y) * cf;
        acc.z += (xs.z + em.z) * cf;
        acc.w += (xs.w + em.w) * cf;
        S += ex;
    }
    // merge the two halves (both end with full sums)
    acc.x += __shfl_xor(acc.x, 32, WAVE);
    acc.y += __shfl_xor(acc.y, 32, WAVE);
    acc.z += __shfl_xor(acc.z, 32, WAVE);
    acc.w += __shfl_xor(acc.w, 32, WAVE);
    S += __shfl_xor(S, 32, WAVE);

    float inv = 1.f / (S + 1e-16f);
    float4 xt = *(const float4*)&xtan[(size_t)wid * 128 + 4 * li];
    float4 y;
    y.x = xt.x + acc.x * inv;
    y.y = xt.y + acc.y * inv;
    y.z = xt.z + acc.z * inv;
    y.w = xt.w + acc.w * inv;

    // LayerNorm: reduce within each 32-lane half (both halves identical)
    float sum = y.x + y.y + y.z + y.w;
    float sq = y.x * y.x + y.y * y.y + y.z * y.z + y.w * y.w;
    #pragma unroll
    for (int m = 1; m < 32; m <<= 1) {
        sum += __shfl_xor(sum, m, WAVE);
        sq  += __shfl_xor(sq, m, WAVE);
    }
    float mu = sum * (1.f / 128.f);
    float var = sq * (1.f / 128.f) - mu * mu;
    float invs = rsqrtf(var + 1e-5f);
    float4 gg = *(const float4*)&g[4 * li];
    float4 bb = *(const float4*)&b[4 * li];
    y.x = (y.x - mu) * invs * gg.x + bb.x;
    y.y = (y.y - mu) * invs * gg.y + bb.y;
    y.z = (y.z - mu) * invs * gg.z + bb.z;
    y.w = (y.w - mu) * invs * gg.w + bb.w;

    // exp map
    float nrm2 = y.x * y.x + y.y * y.y + y.z * y.z + y.w * y.w;
    #pragma unroll
    for (int m = 1; m < 32; m <<= 1) nrm2 += __shfl_xor(nrm2, m, WAVE);
    float nrm = fmaxf(sqrtf(nrm2), 1e-6f);
    float th = sqc * nrm;
    float sc = sinhf(th) / (sqc * nrm);
    float* o = out + (size_t)wid * 129;
    if (lane == 0) o[0] = coshf(th) / sqc;
    // half 0 writes .x/.y, half 1 writes .z/.w (both hold identical values)
    if (half == 0) {
        o[1 + 4 * li] = y.x * sc;
        o[2 + 4 * li] = y.y * sc;
    } else {
        o[3 + 4 * li] = y.z * sc;
        o[4 + 4 * li] = y.w * sc;
    }
}

// ---------------------------------------------------------------------------
extern "C" void kernel_launch(void* const* d_in, const int* in_sizes, int n_in,
                              void* d_out, int out_size, void* d_ws, size_t ws_size,
                              hipStream_t stream) {
    const float* x_hyp = (const float*)d_in[0];
    const int*   ei    = (const int*)d_in[1];
    const int*   et    = (const int*)d_in[2];
    const float* ew    = (const float*)d_in[3];
    const float* lin_w = (const float*)d_in[4];
    const float* lin_b = (const float*)d_in[5];
    const float* ln_g  = (const float*)d_in[6];
    const float* ln_b  = (const float*)d_in[7];
    const float* emb   = (const float*)d_in[8];
    const float* w1    = (const float*)d_in[9];
    const float* b1    = (const float*)d_in[10];
    const float* w2    = (const float*)d_in[11];
    const float* b2    = (const float*)d_in[12];
    const float* sib   = (const float*)d_in[13];
    const float* curv  = (const float*)d_in[14];
    float* out = (float*)d_out;
    float* ws  = (float*)d_ws;

    const int N = in_sizes[0] / 129;
    const int E = in_sizes[2];
    const int L = in_sizes[4] / (128 * 128);
    const int NB = (N + 255) / 256;

    // float region
    float* xtan = ws;                               // N*128
    float* xlin = xtan + (size_t)N * 128;           // N*128
    float* acat = xlin + (size_t)N * 128;           // N*128
    // int region
    int2* epack = (int2*)(acat + (size_t)N * 128);  // E int2
    int* edst   = (int*)(epack + E);                // E
    float* exb  = (float*)(edst + E);               // E
    int* deg    = (int*)(exb + E);                  // N (reused as cursor)
    int* rs     = deg + N;                          // N+1
    int* btot   = rs + N + 1;                       // 256
    float* Wt   = (float*)(btot + 256);             // 128*128
    float* ae   = Wt + 128 * 128;                   // 256

    // ---- CSR build (once; edges static across layers) ----
    hipMemsetAsync(deg, 0, (size_t)N * sizeof(int), stream);
    k_hist<<<(E + 255) / 256, 256, 0, stream>>>(ei, deg, E);
    k_scan1<<<NB, 256, 0, stream>>>(deg, rs, btot, N);
    k_scan2<<<1, 256, 0, stream>>>(btot, NB);
    k_scan3<<<NB, 256, 0, stream>>>(rs, btot, deg /*cursor*/, N, E);
    k_scatter<<<(E + 255) / 256, 256, 0, stream>>>(ei, et, ew, deg /*cursor*/,
                                                   epack, edst, E);

    const float* xin = x_hyp;
    for (int l = 0; l < L; ++l) {
        const float* w1l = w1 + (size_t)l * 384 * 64;
        const float* embl = emb + (size_t)l * 4 * 128;
        k_logmap<<<(N + 3) / 4, 256, 0, stream>>>(xin, xtan, curv + l, N);
        k_build_wt<<<64, 256, 0, stream>>>(w1l, Wt);
        k_prep_ae<<<1, 256, 0, stream>>>(embl, w1l, b1 + (size_t)l * 64, ae);
        gemm128<<<dim3((N + 63) / 64, 2), 256, 0, stream>>>(
            xtan, lin_w + (size_t)l * 128 * 128, lin_b + (size_t)l * 128, xlin, N);
        gemm128<<<dim3((N + 63) / 64, 2), 256, 0, stream>>>(
            xlin, Wt, nullptr, acat, N);
        k_score<<<(E * 16 + 255) / 256, 256, 0, stream>>>(
            epack, edst, acat, ae, w2 + (size_t)l * 64, b2 + l, sib + l, exb, E);
        k_gather<<<(N + 3) / 4, 256, 0, stream>>>(
            rs, epack, exb, xlin, xtan, embl,
            ln_g + (size_t)l * 128, ln_b + (size_t)l * 128, curv + l, out, N);
        xin = out;
    }
}

// Round 4
// 382.620 us; speedup vs baseline: 1.6908x; 1.1644x over previous
//
#include <hip/hip_runtime.h>
#include <hip/hip_bf16.h>
#include <math.h>

#define WAVE 64

typedef __attribute__((ext_vector_type(8))) short bf16x8;
typedef __attribute__((ext_vector_type(4))) float f32x4;

__device__ __forceinline__ float wave_reduce_sum(float v) {
    #pragma unroll
    for (int off = 32; off > 0; off >>= 1) v += __shfl_xor(v, off, WAVE);
    return v;
}

// bf16 <-> f32 helpers (bit-level, RNE on pack)
__device__ __forceinline__ unsigned short f2b(float f) {
    unsigned u = __float_as_uint(f);
    unsigned r = (u + 0x7FFFu + ((u >> 16) & 1u)) >> 16;
    return (unsigned short)r;
}
__device__ __forceinline__ float b2f(unsigned short u) {
    return __uint_as_float(((unsigned)u) << 16);
}

// ---------------------------------------------------------------------------
// log map (x_hyp (N,129) -> x_tan fp32 (N,128) + bf16 copy), one wave/node
// ---------------------------------------------------------------------------
__global__ void k_logmap(const float* __restrict__ xh, float* __restrict__ xtan,
                         unsigned short* __restrict__ xtan_bf,
                         const float* __restrict__ curv, int N) {
    int wid = (blockIdx.x * blockDim.x + threadIdx.x) >> 6;
    int lane = threadIdx.x & 63;
    if (wid >= N) return;
    float c = fminf(fmaxf(curv[0], 0.1f), 10.f);
    float sqc = sqrtf(c);
    const float* row = xh + (size_t)wid * 129;
    float x0 = row[0];
    float s0 = row[1 + lane];
    float s1 = row[65 + lane];
    float nrm2 = wave_reduce_sum(s0 * s0 + s1 * s1);
    float nrm = fmaxf(sqrtf(nrm2), 1e-6f);
    float x0c = fmaxf(sqc * x0, 1.f + 1e-7f);
    float dist = acoshf(x0c) / sqc;
    float f = dist / nrm;
    float v0 = s0 * f, v1 = s1 * f;
    float* o = xtan + (size_t)wid * 128;
    o[lane] = v0;
    o[64 + lane] = v1;
    unsigned short* ob = xtan_bf + (size_t)wid * 128;
    ob[lane] = f2b(v0);
    ob[64 + lane] = f2b(v1);
}

// ---------------------------------------------------------------------------
// lin_w (128x128 fp32) -> bf16
// ---------------------------------------------------------------------------
__global__ void k_conv_linw(const float* __restrict__ in, unsigned short* __restrict__ out) {
    int idx = blockIdx.x * 256 + threadIdx.x;
    out[idx] = f2b(in[idx]);
}

// ---------------------------------------------------------------------------
// Wt bf16 (128x128) from w1 (384x64): Wt[o][i] = o<64 ? w1[i][o] : w1[128+i][o-64]
// ---------------------------------------------------------------------------
__global__ void k_build_wt(const float* __restrict__ w1, unsigned short* __restrict__ Wt) {
    int idx = blockIdx.x * 256 + threadIdx.x;
    int o = idx >> 7, i = idx & 127;
    float v = (o < 64) ? w1[i * 64 + o] : w1[(128 + i) * 64 + (o - 64)];
    Wt[idx] = f2b(v);
}

// ---------------------------------------------------------------------------
// a_e[t][h] = b1[h] + sum_i emb[t][i] * w1[256+i][h]   (T=4, H=64) fp32
// ---------------------------------------------------------------------------
__global__ void k_prep_ae(const float* __restrict__ emb, const float* __restrict__ w1,
                          const float* __restrict__ b1, float* __restrict__ ae) {
    int tid = threadIdx.x;
    int t = tid >> 6, h = tid & 63;
    float s = b1[h];
    #pragma unroll 8
    for (int i = 0; i < 128; ++i) s += emb[t * 128 + i] * w1[(256 + i) * 64 + h];
    ae[tid] = s;
}

// ---------------------------------------------------------------------------
// CSR build
// ---------------------------------------------------------------------------
__global__ void k_hist(const int* __restrict__ ei, int* __restrict__ deg, int E) {
    int e = blockIdx.x * 256 + threadIdx.x;
    if (e < E) atomicAdd(&deg[ei[E + e]], 1);
}

__global__ void k_scan1(const int* __restrict__ deg, int* __restrict__ rs,
                        int* __restrict__ btot, int N) {
    __shared__ int wsum[4];
    int i = blockIdx.x * 256 + threadIdx.x;
    int v = (i < N) ? deg[i] : 0;
    int lane = threadIdx.x & 63, w = threadIdx.x >> 6;
    int x = v;
    #pragma unroll
    for (int off = 1; off < 64; off <<= 1) {
        int t = __shfl_up(x, off, 64);
        if (lane >= off) x += t;
    }
    if (lane == 63) wsum[w] = x;
    __syncthreads();
    int woff = 0;
    for (int j = 0; j < w; ++j) woff += wsum[j];
    int incl = woff + x;
    if (i < N) rs[i] = incl - v;
    if (threadIdx.x == 255) btot[blockIdx.x] = incl;
}

__global__ void k_scan2(int* __restrict__ btot, int nb) {
    __shared__ int wsum[4];
    int i = threadIdx.x;
    int v = (i < nb) ? btot[i] : 0;
    int lane = i & 63, w = i >> 6;
    int x = v;
    #pragma unroll
    for (int off = 1; off < 64; off <<= 1) {
        int t = __shfl_up(x, off, 64);
        if (lane >= off) x += t;
    }
    if (lane == 63) wsum[w] = x;
    __syncthreads();
    int woff = 0;
    for (int j = 0; j < w; ++j) woff += wsum[j];
    int incl = woff + x;
    __syncthreads();
    if (i < nb) btot[i] = incl - v;
}

__global__ void k_scan3(int* __restrict__ rs, const int* __restrict__ btot,
                        int* __restrict__ cursor, int N, int E) {
    int i = blockIdx.x * 256 + threadIdx.x;
    if (i < N) {
        int v = rs[i] + btot[blockIdx.x];
        rs[i] = v;
        cursor[i] = v;
    }
    if (i == 0) rs[N] = E;
}

__global__ void k_scatter(const int* __restrict__ ei, const int* __restrict__ et,
                          const float* __restrict__ ew, int* __restrict__ cursor,
                          int2* __restrict__ epack, int* __restrict__ edst, int E) {
    int e = blockIdx.x * 256 + threadIdx.x;
    if (e >= E) return;
    int dst = ei[E + e];
    int pos = atomicAdd(&cursor[dst], 1);
    int2 r;
    r.x = ei[e] | (et[e] << 24);
    r.y = __float_as_int(ew[e]);
    epack[pos] = r;
    edst[pos] = dst;
}

// ---------------------------------------------------------------------------
// MFMA bf16 GEMM: C[M x 128] = A[M x 128] @ W[128 x 128]^T (+ bias), bf16 io.
// No LDS: A/B fragments are direct 16B global loads (row-major bf16).
// Block = 256 thr = 4 waves; wave does 16 rows x 128 cols; K=128 in 4 steps.
// ---------------------------------------------------------------------------
__global__ __launch_bounds__(256) void gemm_bf(
    const unsigned short* __restrict__ A, const unsigned short* __restrict__ W,
    const float* __restrict__ bias, unsigned short* __restrict__ C, int M)
{
    int wave = threadIdx.x >> 6;
    int lane = threadIdx.x & 63;
    int quad = lane >> 4;
    int l16  = lane & 15;
    int m0 = blockIdx.x * 64 + wave * 16;
    int mrow = m0 + l16;
    int mclamp = mrow < M ? mrow : M - 1;

    f32x4 acc[8];
    #pragma unroll
    for (int nt = 0; nt < 8; ++nt) acc[nt] = (f32x4){0.f, 0.f, 0.f, 0.f};

    #pragma unroll
    for (int kk = 0; kk < 4; ++kk) {
        bf16x8 a = *(const bf16x8*)&A[(size_t)mclamp * 128 + kk * 32 + quad * 8];
        #pragma unroll
        for (int nt = 0; nt < 8; ++nt) {
            bf16x8 b = *(const bf16x8*)&W[(size_t)(nt * 16 + l16) * 128 + kk * 32 + quad * 8];
            acc[nt] = __builtin_amdgcn_mfma_f32_16x16x32_bf16(a, b, acc[nt], 0, 0, 0);
        }
    }
    // C/D layout: col = l16, row_in_tile = quad*4 + r
    #pragma unroll
    for (int nt = 0; nt < 8; ++nt) {
        float bv = bias ? bias[nt * 16 + l16] : 0.f;
        #pragma unroll
        for (int r = 0; r < 4; ++r) {
            int row = m0 + quad * 4 + r;
            if (row < M) C[(size_t)row * 128 + nt * 16 + l16] = f2b(acc[nt][r] + bv);
        }
    }
}

// ---------------------------------------------------------------------------
// Per-edge score: 16 lanes per edge (4 edges/wave), bf16 acat.
// ---------------------------------------------------------------------------
__device__ __forceinline__ float silu(float x) { return x / (1.f + expf(-x)); }

__global__ __launch_bounds__(256) void k_score(
    const int2* __restrict__ epack, const int* __restrict__ edst,
    const unsigned short* __restrict__ acat, const float* __restrict__ ae,
    const float* __restrict__ w2, const float* __restrict__ b2,
    const float* __restrict__ sib, float* __restrict__ exb, int E)
{
    int gid = blockIdx.x * 256 + threadIdx.x;
    int e = gid >> 4;
    int li = threadIdx.x & 15;
    if (e >= E) return;
    int2 r = epack[e];
    int src = r.x & 0xFFFFFF;
    int t = ((unsigned)r.x) >> 24;
    float w = __int_as_float(r.y);
    int dst = edst[e];

    ushort4 adu = *(const ushort4*)&acat[(size_t)dst * 128 + 4 * li];
    ushort4 asu = *(const ushort4*)&acat[(size_t)src * 128 + 64 + 4 * li];
    float4 av = *(const float4*)&ae[t * 64 + 4 * li];
    float4 wv = *(const float4*)&w2[4 * li];
    float d = silu(b2f(adu.x) + b2f(asu.x) + av.x) * wv.x
            + silu(b2f(adu.y) + b2f(asu.y) + av.y) * wv.y
            + silu(b2f(adu.z) + b2f(asu.z) + av.z) * wv.z
            + silu(b2f(adu.w) + b2f(asu.w) + av.w) * wv.w;
    #pragma unroll
    for (int m = 1; m < 16; m <<= 1) d += __shfl_xor(d, m, WAVE);
    if (li == 0) {
        float s = d + b2[0] + logf(fmaxf(w, 1e-6f));
        if (t == 1) s += sib[0];
        exb[e] = expf(s);
    }
}

// ---------------------------------------------------------------------------
// Per-node gather: one wave per node, 2 edges/iter via 32-lane halves.
// xlin is bf16; xtan fp32; fused LN + exp-map.
// ---------------------------------------------------------------------------
__global__ __launch_bounds__(256) void k_gather(
    const int* __restrict__ rs, const int2* __restrict__ epack,
    const float* __restrict__ exb, const unsigned short* __restrict__ xlin,
    const float* __restrict__ xtan, const float* __restrict__ emb,
    const float* __restrict__ g, const float* __restrict__ b,
    const float* __restrict__ curv, float* __restrict__ out, int N)
{
    int wid = (blockIdx.x * blockDim.x + threadIdx.x) >> 6;
    int lane = threadIdx.x & 63;
    if (wid >= N) return;
    int half = lane >> 5;
    int li = lane & 31;
    float c = fminf(fmaxf(curv[0], 0.1f), 10.f);
    float sqc = sqrtf(c);
    int p0 = rs[wid], p1 = rs[wid + 1];

    float4 acc = make_float4(0.f, 0.f, 0.f, 0.f);
    float S = 0.f;
    for (int p = p0 + half; p < p1; p += 2) {
        int2 r = epack[p];
        int src = r.x & 0xFFFFFF;
        int t = ((unsigned)r.x) >> 24;
        float w = __int_as_float(r.y);
        float ex = exb[p];
        float cf = ex * w;
        ushort4 xu = *(const ushort4*)&xlin[(size_t)src * 128 + 4 * li];
        float4 em = *(const float4*)&emb[t * 128 + 4 * li];
        acc.x += (b2f(xu.x) + em.x) * cf;
        acc.y += (b2f(xu.y) + em.y) * cf;
        acc.z += (b2f(xu.z) + em.z) * cf;
        acc.w += (b2f(xu.w) + em.w) * cf;
        S += ex;
    }
    acc.x += __shfl_xor(acc.x, 32, WAVE);
    acc.y += __shfl_xor(acc.y, 32, WAVE);
    acc.z += __shfl_xor(acc.z, 32, WAVE);
    acc.w += __shfl_xor(acc.w, 32, WAVE);
    S += __shfl_xor(S, 32, WAVE);

    float inv = 1.f / (S + 1e-16f);
    float4 xt = *(const float4*)&xtan[(size_t)wid * 128 + 4 * li];
    float4 y;
    y.x = xt.x + acc.x * inv;
    y.y = xt.y + acc.y * inv;
    y.z = xt.z + acc.z * inv;
    y.w = xt.w + acc.w * inv;

    float sum = y.x + y.y + y.z + y.w;
    float sq = y.x * y.x + y.y * y.y + y.z * y.z + y.w * y.w;
    #pragma unroll
    for (int m = 1; m < 32; m <<= 1) {
        sum += __shfl_xor(sum, m, WAVE);
        sq  += __shfl_xor(sq, m, WAVE);
    }
    float mu = sum * (1.f / 128.f);
    float var = sq * (1.f / 128.f) - mu * mu;
    float invs = rsqrtf(var + 1e-5f);
    float4 gg = *(const float4*)&g[4 * li];
    float4 bb = *(const float4*)&b[4 * li];
    y.x = (y.x - mu) * invs * gg.x + bb.x;
    y.y = (y.y - mu) * invs * gg.y + bb.y;
    y.z = (y.z - mu) * invs * gg.z + bb.z;
    y.w = (y.w - mu) * invs * gg.w + bb.w;

    float nrm2 = y.x * y.x + y.y * y.y + y.z * y.z + y.w * y.w;
    #pragma unroll
    for (int m = 1; m < 32; m <<= 1) nrm2 += __shfl_xor(nrm2, m, WAVE);
    float nrm = fmaxf(sqrtf(nrm2), 1e-6f);
    float th = sqc * nrm;
    float sc = sinhf(th) / (sqc * nrm);
    float* o = out + (size_t)wid * 129;
    if (lane == 0) o[0] = coshf(th) / sqc;
    if (half == 0) {
        o[1 + 4 * li] = y.x * sc;
        o[2 + 4 * li] = y.y * sc;
    } else {
        o[3 + 4 * li] = y.z * sc;
        o[4 + 4 * li] = y.w * sc;
    }
}

// ---------------------------------------------------------------------------
extern "C" void kernel_launch(void* const* d_in, const int* in_sizes, int n_in,
                              void* d_out, int out_size, void* d_ws, size_t ws_size,
                              hipStream_t stream) {
    const float* x_hyp = (const float*)d_in[0];
    const int*   ei    = (const int*)d_in[1];
    const int*   et    = (const int*)d_in[2];
    const float* ew    = (const float*)d_in[3];
    const float* lin_w = (const float*)d_in[4];
    const float* lin_b = (const float*)d_in[5];
    const float* ln_g  = (const float*)d_in[6];
    const float* ln_b  = (const float*)d_in[7];
    const float* emb   = (const float*)d_in[8];
    const float* w1    = (const float*)d_in[9];
    const float* b1    = (const float*)d_in[10];
    const float* w2    = (const float*)d_in[11];
    const float* b2    = (const float*)d_in[12];
    const float* sib   = (const float*)d_in[13];
    const float* curv  = (const float*)d_in[14];
    float* out = (float*)d_out;
    float* ws  = (float*)d_ws;

    const int N = in_sizes[0] / 129;
    const int E = in_sizes[2];
    const int L = in_sizes[4] / (128 * 128);
    const int NB = (N + 255) / 256;

    // layout (N*128*4 then 3x N*128*2 keeps everything 16B-aligned; N mult of 8)
    float* xtan = ws;                                             // N*128 f32
    unsigned short* xtan_bf = (unsigned short*)(xtan + (size_t)N * 128);  // N*128
    unsigned short* xlin_bf = xtan_bf + (size_t)N * 128;          // N*128
    unsigned short* acat_bf = xlin_bf + (size_t)N * 128;          // N*128
    int2* epack = (int2*)(acat_bf + (size_t)N * 128);             // E
    int* edst   = (int*)(epack + E);                              // E
    float* exb  = (float*)(edst + E);                             // E
    unsigned short* lw_bf = (unsigned short*)(exb + E);           // 128*128
    unsigned short* Wt_bf = lw_bf + 128 * 128;                    // 128*128
    float* ae   = (float*)(Wt_bf + 128 * 128);                    // 256
    int* deg    = (int*)(ae + 256);                               // N (cursor)
    int* rs     = deg + N;                                        // N+1
    int* btot   = rs + N + 1;                                     // 256

    // ---- CSR build (once; edges static across layers) ----
    hipMemsetAsync(deg, 0, (size_t)N * sizeof(int), stream);
    k_hist<<<(E + 255) / 256, 256, 0, stream>>>(ei, deg, E);
    k_scan1<<<NB, 256, 0, stream>>>(deg, rs, btot, N);
    k_scan2<<<1, 256, 0, stream>>>(btot, NB);
    k_scan3<<<NB, 256, 0, stream>>>(rs, btot, deg /*cursor*/, N, E);
    k_scatter<<<(E + 255) / 256, 256, 0, stream>>>(ei, et, ew, deg /*cursor*/,
                                                   epack, edst, E);

    const float* xin = x_hyp;
    for (int l = 0; l < L; ++l) {
        const float* w1l = w1 + (size_t)l * 384 * 64;
        const float* embl = emb + (size_t)l * 4 * 128;
        k_logmap<<<(N + 3) / 4, 256, 0, stream>>>(xin, xtan, xtan_bf, curv + l, N);
        k_conv_linw<<<64, 256, 0, stream>>>(lin_w + (size_t)l * 128 * 128, lw_bf);
        k_build_wt<<<64, 256, 0, stream>>>(w1l, Wt_bf);
        k_prep_ae<<<1, 256, 0, stream>>>(embl, w1l, b1 + (size_t)l * 64, ae);
        gemm_bf<<<(N + 63) / 64, 256, 0, stream>>>(
            xtan_bf, lw_bf, lin_b + (size_t)l * 128, xlin_bf, N);
        gemm_bf<<<(N + 63) / 64, 256, 0, stream>>>(
            xlin_bf, Wt_bf, nullptr, acat_bf, N);
        k_score<<<(E * 16 + 255) / 256, 256, 0, stream>>>(
            epack, edst, acat_bf, ae, w2 + (size_t)l * 64, b2 + l, sib + l, exb, E);
        k_gather<<<(N + 3) / 4, 256, 0, stream>>>(
            rs, epack, exb, xlin_bf, xtan, embl,
            ln_g + (size_t)l * 128, ln_b + (size_t)l * 128, curv + l, out, N);
        xin = out;
    }
}

// Round 5
// 345.604 us; speedup vs baseline: 1.8719x; 1.1071x over previous
//
#include <hip/hip_runtime.h>
#include <hip/hip_bf16.h>
#include <math.h>

#define WAVE 64

typedef __attribute__((ext_vector_type(8))) short bf16x8;
typedef __attribute__((ext_vector_type(4))) float f32x4;

__device__ __forceinline__ float wave_reduce_sum(float v) {
    #pragma unroll
    for (int off = 32; off > 0; off >>= 1) v += __shfl_xor(v, off, WAVE);
    return v;
}

// bf16 <-> f32 helpers (bit-level, RNE on pack)
__device__ __forceinline__ unsigned short f2b(float f) {
    unsigned u = __float_as_uint(f);
    unsigned r = (u + 0x7FFFu + ((u >> 16) & 1u)) >> 16;
    return (unsigned short)r;
}
__device__ __forceinline__ float b2f(unsigned short u) {
    return __uint_as_float(((unsigned)u) << 16);
}

// ---------------------------------------------------------------------------
// log map (x_hyp (N,129) -> x_tan bf16 (N,128)), one wave per node
// ---------------------------------------------------------------------------
__global__ void k_logmap(const float* __restrict__ xh,
                         unsigned short* __restrict__ xtan_bf,
                         const float* __restrict__ curv, int N) {
    int wid = (blockIdx.x * blockDim.x + threadIdx.x) >> 6;
    int lane = threadIdx.x & 63;
    if (wid >= N) return;
    float c = fminf(fmaxf(curv[0], 0.1f), 10.f);
    float sqc = sqrtf(c);
    const float* row = xh + (size_t)wid * 129;
    float x0 = row[0];
    float s0 = row[1 + lane];
    float s1 = row[65 + lane];
    float nrm2 = wave_reduce_sum(s0 * s0 + s1 * s1);
    float nrm = fmaxf(sqrtf(nrm2), 1e-6f);
    float x0c = fmaxf(sqc * x0, 1.f + 1e-7f);
    float dist = acoshf(x0c) / sqc;
    float f = dist / nrm;
    unsigned short* ob = xtan_bf + (size_t)wid * 128;
    ob[lane] = f2b(s0 * f);
    ob[64 + lane] = f2b(s1 * f);
}

// ---------------------------------------------------------------------------
// Prep (one kernel): lw_bf = bf16(lin_w); Wt_bf from w1; ae = b1 + emb@w1[256:]
// grid = 129 blocks x 256
// ---------------------------------------------------------------------------
__global__ void k_prep(const float* __restrict__ lin_w, const float* __restrict__ w1,
                       const float* __restrict__ b1, const float* __restrict__ emb,
                       unsigned short* __restrict__ lw_bf,
                       unsigned short* __restrict__ Wt_bf, float* __restrict__ ae) {
    int bx = blockIdx.x, tid = threadIdx.x;
    if (bx < 64) {
        int idx = bx * 256 + tid;
        lw_bf[idx] = f2b(lin_w[idx]);
    } else if (bx < 128) {
        int idx = (bx - 64) * 256 + tid;
        int o = idx >> 7, i = idx & 127;
        float v = (o < 64) ? w1[i * 64 + o] : w1[(128 + i) * 64 + (o - 64)];
        Wt_bf[idx] = f2b(v);
    } else {
        int t = tid >> 6, h = tid & 63;
        float s = b1[h];
        #pragma unroll 8
        for (int i = 0; i < 128; ++i) s += emb[t * 128 + i] * w1[(256 + i) * 64 + h];
        ae[tid] = s;
    }
}

// ---------------------------------------------------------------------------
// CSR build
// ---------------------------------------------------------------------------
__global__ void k_hist(const int* __restrict__ ei, int* __restrict__ deg, int E) {
    int e = blockIdx.x * 256 + threadIdx.x;
    if (e < E) atomicAdd(&deg[ei[E + e]], 1);
}

__global__ void k_scan1(const int* __restrict__ deg, int* __restrict__ rs,
                        int* __restrict__ btot, int N) {
    __shared__ int wsum[4];
    int i = blockIdx.x * 256 + threadIdx.x;
    int v = (i < N) ? deg[i] : 0;
    int lane = threadIdx.x & 63, w = threadIdx.x >> 6;
    int x = v;
    #pragma unroll
    for (int off = 1; off < 64; off <<= 1) {
        int t = __shfl_up(x, off, 64);
        if (lane >= off) x += t;
    }
    if (lane == 63) wsum[w] = x;
    __syncthreads();
    int woff = 0;
    for (int j = 0; j < w; ++j) woff += wsum[j];
    int incl = woff + x;
    if (i < N) rs[i] = incl - v;
    if (threadIdx.x == 255) btot[blockIdx.x] = incl;
}

__global__ void k_scan2(int* __restrict__ btot, int nb) {
    __shared__ int wsum[4];
    int i = threadIdx.x;
    int v = (i < nb) ? btot[i] : 0;
    int lane = i & 63, w = i >> 6;
    int x = v;
    #pragma unroll
    for (int off = 1; off < 64; off <<= 1) {
        int t = __shfl_up(x, off, 64);
        if (lane >= off) x += t;
    }
    if (lane == 63) wsum[w] = x;
    __syncthreads();
    int woff = 0;
    for (int j = 0; j < w; ++j) woff += wsum[j];
    int incl = woff + x;
    __syncthreads();
    if (i < nb) btot[i] = incl - v;
}

__global__ void k_scan3(int* __restrict__ rs, const int* __restrict__ btot,
                        int* __restrict__ cursor, int N, int E) {
    int i = blockIdx.x * 256 + threadIdx.x;
    if (i < N) {
        int v = rs[i] + btot[blockIdx.x];
        rs[i] = v;
        cursor[i] = v;
    }
    if (i == 0) rs[N] = E;
}

__global__ void k_scatter(const int* __restrict__ ei, const int* __restrict__ et,
                          const float* __restrict__ ew, int* __restrict__ cursor,
                          int2* __restrict__ epack, int* __restrict__ edst, int E) {
    int e = blockIdx.x * 256 + threadIdx.x;
    if (e >= E) return;
    int dst = ei[E + e];
    int pos = atomicAdd(&cursor[dst], 1);
    int2 r;
    r.x = ei[e] | (et[e] << 24);
    r.y = __float_as_int(ew[e]);
    epack[pos] = r;
    edst[pos] = dst;
}

// ---------------------------------------------------------------------------
// Fused double GEMM (MFMA bf16):
//   xlin = xtan @ lin_w^T + lin_b     (written to global + LDS)
//   acat = xlin @ Wt^T                (from LDS fragments)
// Block = 256 thr (4 waves), 64 rows/block, K=128 in 4 MFMA steps.
// LDS tile pitch 136 shorts (16B-aligned rows, breaks 256B stride aliasing).
// ---------------------------------------------------------------------------
__global__ __launch_bounds__(256) void gemm_fused(
    const unsigned short* __restrict__ A, const unsigned short* __restrict__ LW,
    const unsigned short* __restrict__ WT, const float* __restrict__ bias,
    unsigned short* __restrict__ xlin, unsigned short* __restrict__ acat, int M)
{
    __shared__ unsigned short xs[64 * 136];
    int wave = threadIdx.x >> 6;
    int lane = threadIdx.x & 63;
    int quad = lane >> 4;
    int l16  = lane & 15;
    int m0w = blockIdx.x * 64 + wave * 16;
    int row = m0w + l16;
    int rowc = row < M ? row : M - 1;

    // ---- GEMM 1: A-fragments direct from global ----
    bf16x8 a[4];
    #pragma unroll
    for (int kk = 0; kk < 4; ++kk)
        a[kk] = *(const bf16x8*)&A[(size_t)rowc * 128 + kk * 32 + quad * 8];

    f32x4 acc[8];
    #pragma unroll
    for (int nt = 0; nt < 8; ++nt) acc[nt] = (f32x4){0.f, 0.f, 0.f, 0.f};
    #pragma unroll
    for (int kk = 0; kk < 4; ++kk) {
        #pragma unroll
        for (int nt = 0; nt < 8; ++nt) {
            bf16x8 b = *(const bf16x8*)&LW[(size_t)(nt * 16 + l16) * 128 + kk * 32 + quad * 8];
            acc[nt] = __builtin_amdgcn_mfma_f32_16x16x32_bf16(a[kk], b, acc[nt], 0, 0, 0);
        }
    }
    // epilogue 1 -> LDS (C layout: col=l16, row=quad*4+r), +bias
    #pragma unroll
    for (int nt = 0; nt < 8; ++nt) {
        float bv = bias[nt * 16 + l16];
        #pragma unroll
        for (int r = 0; r < 4; ++r) {
            int lrow = wave * 16 + quad * 4 + r;
            xs[lrow * 136 + nt * 16 + l16] = f2b(acc[nt][r] + bv);
        }
    }
    __syncthreads();

    // ---- read back A-fragments for GEMM 2 + coalesced global xlin write ----
    bf16x8 a2[4];
    int lrowr = wave * 16 + l16;
    #pragma unroll
    for (int kk = 0; kk < 4; ++kk) {
        a2[kk] = *(const bf16x8*)&xs[lrowr * 136 + kk * 32 + quad * 8];
        if (row < M)
            *(bf16x8*)&xlin[(size_t)row * 128 + kk * 32 + quad * 8] = a2[kk];
    }

    // ---- GEMM 2 ----
    f32x4 acc2[8];
    #pragma unroll
    for (int nt = 0; nt < 8; ++nt) acc2[nt] = (f32x4){0.f, 0.f, 0.f, 0.f};
    #pragma unroll
    for (int kk = 0; kk < 4; ++kk) {
        #pragma unroll
        for (int nt = 0; nt < 8; ++nt) {
            bf16x8 b = *(const bf16x8*)&WT[(size_t)(nt * 16 + l16) * 128 + kk * 32 + quad * 8];
            acc2[nt] = __builtin_amdgcn_mfma_f32_16x16x32_bf16(a2[kk], b, acc2[nt], 0, 0, 0);
        }
    }
    #pragma unroll
    for (int nt = 0; nt < 8; ++nt) {
        #pragma unroll
        for (int r = 0; r < 4; ++r) {
            int rr = m0w + quad * 4 + r;
            if (rr < M) acat[(size_t)rr * 128 + nt * 16 + l16] = f2b(acc2[nt][r]);
        }
    }
}

// ---------------------------------------------------------------------------
// Per-edge score: 16 lanes per edge (4 edges/wave), bf16 acat.
// ---------------------------------------------------------------------------
__device__ __forceinline__ float silu(float x) { return x / (1.f + expf(-x)); }

__global__ __launch_bounds__(256) void k_score(
    const int2* __restrict__ epack, const int* __restrict__ edst,
    const unsigned short* __restrict__ acat, const float* __restrict__ ae,
    const float* __restrict__ w2, const float* __restrict__ b2,
    const float* __restrict__ sib, float* __restrict__ exb, int E)
{
    int gid = blockIdx.x * 256 + threadIdx.x;
    int e = gid >> 4;
    int li = threadIdx.x & 15;
    if (e >= E) return;
    int2 r = epack[e];
    int src = r.x & 0xFFFFFF;
    int t = ((unsigned)r.x) >> 24;
    float w = __int_as_float(r.y);
    int dst = edst[e];

    ushort4 adu = *(const ushort4*)&acat[(size_t)dst * 128 + 4 * li];
    ushort4 asu = *(const ushort4*)&acat[(size_t)src * 128 + 64 + 4 * li];
    float4 av = *(const float4*)&ae[t * 64 + 4 * li];
    float4 wv = *(const float4*)&w2[4 * li];
    float d = silu(b2f(adu.x) + b2f(asu.x) + av.x) * wv.x
            + silu(b2f(adu.y) + b2f(asu.y) + av.y) * wv.y
            + silu(b2f(adu.z) + b2f(asu.z) + av.z) * wv.z
            + silu(b2f(adu.w) + b2f(asu.w) + av.w) * wv.w;
    #pragma unroll
    for (int m = 1; m < 16; m <<= 1) d += __shfl_xor(d, m, WAVE);
    if (li == 0) {
        float s = d + b2[0] + logf(fmaxf(w, 1e-6f));
        if (t == 1) s += sib[0];
        exb[e] = expf(s);
    }
}

// ---------------------------------------------------------------------------
// Per-node gather: one wave per node, 2 edges/iter via 32-lane halves.
// xlin/xtan bf16; fused LN + exp-map.
// ---------------------------------------------------------------------------
__global__ __launch_bounds__(256) void k_gather(
    const int* __restrict__ rs, const int2* __restrict__ epack,
    const float* __restrict__ exb, const unsigned short* __restrict__ xlin,
    const unsigned short* __restrict__ xtan, const float* __restrict__ emb,
    const float* __restrict__ g, const float* __restrict__ b,
    const float* __restrict__ curv, float* __restrict__ out, int N)
{
    int wid = (blockIdx.x * blockDim.x + threadIdx.x) >> 6;
    int lane = threadIdx.x & 63;
    if (wid >= N) return;
    int half = lane >> 5;
    int li = lane & 31;
    float c = fminf(fmaxf(curv[0], 0.1f), 10.f);
    float sqc = sqrtf(c);
    int p0 = rs[wid], p1 = rs[wid + 1];

    float4 acc = make_float4(0.f, 0.f, 0.f, 0.f);
    float S = 0.f;
    for (int p = p0 + half; p < p1; p += 2) {
        int2 r = epack[p];
        int src = r.x & 0xFFFFFF;
        int t = ((unsigned)r.x) >> 24;
        float w = __int_as_float(r.y);
        float ex = exb[p];
        float cf = ex * w;
        ushort4 xu = *(const ushort4*)&xlin[(size_t)src * 128 + 4 * li];
        float4 em = *(const float4*)&emb[t * 128 + 4 * li];
        acc.x += (b2f(xu.x) + em.x) * cf;
        acc.y += (b2f(xu.y) + em.y) * cf;
        acc.z += (b2f(xu.z) + em.z) * cf;
        acc.w += (b2f(xu.w) + em.w) * cf;
        S += ex;
    }
    acc.x += __shfl_xor(acc.x, 32, WAVE);
    acc.y += __shfl_xor(acc.y, 32, WAVE);
    acc.z += __shfl_xor(acc.z, 32, WAVE);
    acc.w += __shfl_xor(acc.w, 32, WAVE);
    S += __shfl_xor(S, 32, WAVE);

    float inv = 1.f / (S + 1e-16f);
    ushort4 xtu = *(const ushort4*)&xtan[(size_t)wid * 128 + 4 * li];
    float4 y;
    y.x = b2f(xtu.x) + acc.x * inv;
    y.y = b2f(xtu.y) + acc.y * inv;
    y.z = b2f(xtu.z) + acc.z * inv;
    y.w = b2f(xtu.w) + acc.w * inv;

    float sum = y.x + y.y + y.z + y.w;
    float sq = y.x * y.x + y.y * y.y + y.z * y.z + y.w * y.w;
    #pragma unroll
    for (int m = 1; m < 32; m <<= 1) {
        sum += __shfl_xor(sum, m, WAVE);
        sq  += __shfl_xor(sq, m, WAVE);
    }
    float mu = sum * (1.f / 128.f);
    float var = sq * (1.f / 128.f) - mu * mu;
    float invs = rsqrtf(var + 1e-5f);
    float4 gg = *(const float4*)&g[4 * li];
    float4 bb = *(const float4*)&b[4 * li];
    y.x = (y.x - mu) * invs * gg.x + bb.x;
    y.y = (y.y - mu) * invs * gg.y + bb.y;
    y.z = (y.z - mu) * invs * gg.z + bb.z;
    y.w = (y.w - mu) * invs * gg.w + bb.w;

    float nrm2 = y.x * y.x + y.y * y.y + y.z * y.z + y.w * y.w;
    #pragma unroll
    for (int m = 1; m < 32; m <<= 1) nrm2 += __shfl_xor(nrm2, m, WAVE);
    float nrm = fmaxf(sqrtf(nrm2), 1e-6f);
    float th = sqc * nrm;
    float sc = sinhf(th) / (sqc * nrm);
    float* o = out + (size_t)wid * 129;
    if (lane == 0) o[0] = coshf(th) / sqc;
    if (half == 0) {
        o[1 + 4 * li] = y.x * sc;
        o[2 + 4 * li] = y.y * sc;
    } else {
        o[3 + 4 * li] = y.z * sc;
        o[4 + 4 * li] = y.w * sc;
    }
}

// ---------------------------------------------------------------------------
extern "C" void kernel_launch(void* const* d_in, const int* in_sizes, int n_in,
                              void* d_out, int out_size, void* d_ws, size_t ws_size,
                              hipStream_t stream) {
    const float* x_hyp = (const float*)d_in[0];
    const int*   ei    = (const int*)d_in[1];
    const int*   et    = (const int*)d_in[2];
    const float* ew    = (const float*)d_in[3];
    const float* lin_w = (const float*)d_in[4];
    const float* lin_b = (const float*)d_in[5];
    const float* ln_g  = (const float*)d_in[6];
    const float* ln_b  = (const float*)d_in[7];
    const float* emb   = (const float*)d_in[8];
    const float* w1    = (const float*)d_in[9];
    const float* b1    = (const float*)d_in[10];
    const float* w2    = (const float*)d_in[11];
    const float* b2    = (const float*)d_in[12];
    const float* sib   = (const float*)d_in[13];
    const float* curv  = (const float*)d_in[14];
    float* out = (float*)d_out;
    float* ws  = (float*)d_ws;

    const int N = in_sizes[0] / 129;
    const int E = in_sizes[2];
    const int L = in_sizes[4] / (128 * 128);
    const int NB = (N + 255) / 256;

    unsigned short* xtan_bf = (unsigned short*)ws;                // N*128
    unsigned short* xlin_bf = xtan_bf + (size_t)N * 128;          // N*128
    unsigned short* acat_bf = xlin_bf + (size_t)N * 128;          // N*128
    int2* epack = (int2*)(acat_bf + (size_t)N * 128);             // E
    int* edst   = (int*)(epack + E);                              // E
    float* exb  = (float*)(edst + E);                             // E
    unsigned short* lw_bf = (unsigned short*)(exb + E);           // 128*128
    unsigned short* Wt_bf = lw_bf + 128 * 128;                    // 128*128
    float* ae   = (float*)(Wt_bf + 128 * 128);                    // 256
    int* deg    = (int*)(ae + 256);                               // N (cursor)
    int* rs     = deg + N;                                        // N+1
    int* btot   = rs + N + 1;                                     // 256

    // ---- CSR build (once; edges static across layers) ----
    hipMemsetAsync(deg, 0, (size_t)N * sizeof(int), stream);
    k_hist<<<(E + 255) / 256, 256, 0, stream>>>(ei, deg, E);
    k_scan1<<<NB, 256, 0, stream>>>(deg, rs, btot, N);
    k_scan2<<<1, 256, 0, stream>>>(btot, NB);
    k_scan3<<<NB, 256, 0, stream>>>(rs, btot, deg /*cursor*/, N, E);
    k_scatter<<<(E + 255) / 256, 256, 0, stream>>>(ei, et, ew, deg /*cursor*/,
                                                   epack, edst, E);

    const float* xin = x_hyp;
    for (int l = 0; l < L; ++l) {
        const float* w1l = w1 + (size_t)l * 384 * 64;
        const float* embl = emb + (size_t)l * 4 * 128;
        k_logmap<<<(N + 3) / 4, 256, 0, stream>>>(xin, xtan_bf, curv + l, N);
        k_prep<<<129, 256, 0, stream>>>(lin_w + (size_t)l * 128 * 128, w1l,
                                        b1 + (size_t)l * 64, embl,
                                        lw_bf, Wt_bf, ae);
        gemm_fused<<<(N + 63) / 64, 256, 0, stream>>>(
            xtan_bf, lw_bf, Wt_bf, lin_b + (size_t)l * 128, xlin_bf, acat_bf, N);
        k_score<<<(E * 16 + 255) / 256, 256, 0, stream>>>(
            epack, edst, acat_bf, ae, w2 + (size_t)l * 64, b2 + l, sib + l, exb, E);
        k_gather<<<(N + 3) / 4, 256, 0, stream>>>(
            rs, epack, exb, xlin_bf, xtan_bf, embl,
            ln_g + (size_t)l * 128, ln_b + (size_t)l * 128, curv + l, out, N);
        xin = out;
    }
}

// Round 6
// 317.112 us; speedup vs baseline: 2.0401x; 1.0898x over previous
//
#include <hip/hip_runtime.h>
#include <hip/hip_bf16.h>
#include <math.h>

#define WAVE 64

typedef __attribute__((ext_vector_type(8))) short bf16x8;
typedef __attribute__((ext_vector_type(4))) float f32x4;

__device__ __forceinline__ float wave_reduce_sum(float v) {
    #pragma unroll
    for (int off = 32; off > 0; off >>= 1) v += __shfl_xor(v, off, WAVE);
    return v;
}

// bf16 <-> f32 helpers (bit-level, RNE on pack)
__device__ __forceinline__ unsigned short f2b(float f) {
    unsigned u = __float_as_uint(f);
    unsigned r = (u + 0x7FFFu + ((u >> 16) & 1u)) >> 16;
    return (unsigned short)r;
}
__device__ __forceinline__ float b2f(unsigned short u) {
    return __uint_as_float(((unsigned)u) << 16);
}
__device__ __forceinline__ float silu(float x) { return x / (1.f + expf(-x)); }

// ---------------------------------------------------------------------------
// Prep (all layers, one dispatch): lw_bf = bf16(lin_w); Wt_bf from w1;
// ae = b1 + emb @ w1[256:].  grid = L*129 blocks x 256.
// ---------------------------------------------------------------------------
__global__ void k_prep(const float* __restrict__ lin_w, const float* __restrict__ w1,
                       const float* __restrict__ b1, const float* __restrict__ emb,
                       unsigned short* __restrict__ lw_bf,
                       unsigned short* __restrict__ Wt_bf, float* __restrict__ ae) {
    int l = blockIdx.x / 129, bx = blockIdx.x % 129, tid = threadIdx.x;
    const float* lwl = lin_w + (size_t)l * 16384;
    const float* w1l = w1 + (size_t)l * 384 * 64;
    if (bx < 64) {
        int idx = bx * 256 + tid;
        lw_bf[l * 16384 + idx] = f2b(lwl[idx]);
    } else if (bx < 128) {
        int idx = (bx - 64) * 256 + tid;
        int o = idx >> 7, i = idx & 127;
        float v = (o < 64) ? w1l[i * 64 + o] : w1l[(128 + i) * 64 + (o - 64)];
        Wt_bf[l * 16384 + idx] = f2b(v);
    } else {
        int t = tid >> 6, h = tid & 63;
        float s = b1[l * 64 + h];
        #pragma unroll 8
        for (int i = 0; i < 128; ++i)
            s += emb[l * 512 + t * 128 + i] * w1l[(256 + i) * 64 + h];
        ae[l * 256 + tid] = s;
    }
}

// ---------------------------------------------------------------------------
// CSR build
// ---------------------------------------------------------------------------
__global__ void k_hist(const int* __restrict__ ei, int* __restrict__ deg, int E) {
    int e = blockIdx.x * 256 + threadIdx.x;
    if (e < E) atomicAdd(&deg[ei[E + e]], 1);
}

__global__ void k_scan1(const int* __restrict__ deg, int* __restrict__ rs,
                        int* __restrict__ btot, int N) {
    __shared__ int wsum[4];
    int i = blockIdx.x * 256 + threadIdx.x;
    int v = (i < N) ? deg[i] : 0;
    int lane = threadIdx.x & 63, w = threadIdx.x >> 6;
    int x = v;
    #pragma unroll
    for (int off = 1; off < 64; off <<= 1) {
        int t = __shfl_up(x, off, 64);
        if (lane >= off) x += t;
    }
    if (lane == 63) wsum[w] = x;
    __syncthreads();
    int woff = 0;
    for (int j = 0; j < w; ++j) woff += wsum[j];
    int incl = woff + x;
    if (i < N) rs[i] = incl - v;
    if (threadIdx.x == 255) btot[blockIdx.x] = incl;
}

__global__ void k_scan2(int* __restrict__ btot, int nb) {
    __shared__ int wsum[4];
    int i = threadIdx.x;
    int v = (i < nb) ? btot[i] : 0;
    int lane = i & 63, w = i >> 6;
    int x = v;
    #pragma unroll
    for (int off = 1; off < 64; off <<= 1) {
        int t = __shfl_up(x, off, 64);
        if (lane >= off) x += t;
    }
    if (lane == 63) wsum[w] = x;
    __syncthreads();
    int woff = 0;
    for (int j = 0; j < w; ++j) woff += wsum[j];
    int incl = woff + x;
    __syncthreads();
    if (i < nb) btot[i] = incl - v;
}

__global__ void k_scan3(int* __restrict__ rs, const int* __restrict__ btot,
                        int* __restrict__ cursor, int N, int E) {
    int i = blockIdx.x * 256 + threadIdx.x;
    if (i < N) {
        int v = rs[i] + btot[blockIdx.x];
        rs[i] = v;
        cursor[i] = v;
    }
    if (i == 0) rs[N] = E;
}

__global__ void k_scatter(const int* __restrict__ ei, const int* __restrict__ et,
                          const float* __restrict__ ew, int* __restrict__ cursor,
                          int2* __restrict__ epack, int E) {
    int e = blockIdx.x * 256 + threadIdx.x;
    if (e >= E) return;
    int dst = ei[E + e];
    int pos = atomicAdd(&cursor[dst], 1);
    int2 r;
    r.x = ei[e] | (et[e] << 24);
    r.y = __float_as_int(ew[e]);
    epack[pos] = r;
}

// ---------------------------------------------------------------------------
// k_A: [optional logmap] + fused double GEMM (MFMA bf16).
//   from_hyp: A-fragments computed from x_hyp (129-stride fp32) via in-register
//             logmap (cross-quad norm reduce), xtan_bf written as side-effect.
//   else:     A-fragments loaded from xtan_bf.
//   xlin = xtan @ lin_w^T + lin_b ; acat = xlin @ Wt^T
// Block = 256 thr (4 waves), 64 rows/block. LDS pitch 136 shorts.
// ---------------------------------------------------------------------------
__global__ __launch_bounds__(256) void k_A(
    const float* __restrict__ xh, unsigned short* __restrict__ xtan_bf,
    int from_hyp,
    const unsigned short* __restrict__ LW, const unsigned short* __restrict__ WT,
    const float* __restrict__ bias,
    unsigned short* __restrict__ xlin, unsigned short* __restrict__ acat,
    const float* __restrict__ curv, int M)
{
    __shared__ unsigned short xs[64 * 136];
    int wave = threadIdx.x >> 6;
    int lane = threadIdx.x & 63;
    int quad = lane >> 4;
    int l16  = lane & 15;
    int m0w = blockIdx.x * 64 + wave * 16;
    int row = m0w + l16;
    int rowc = row < M ? row : M - 1;

    bf16x8 a[4];
    if (from_hyp) {
        float c = fminf(fmaxf(curv[0], 0.1f), 10.f);
        float sqc = sqrtf(c);
        const float* xr = xh + (size_t)rowc * 129;
        float x0 = xr[0];
        float vals[4][8];
        float n2 = 0.f;
        #pragma unroll
        for (int kk = 0; kk < 4; ++kk)
            #pragma unroll
            for (int j = 0; j < 8; ++j) {
                float v = xr[1 + kk * 32 + quad * 8 + j];
                vals[kk][j] = v;
                n2 += v * v;
            }
        // reduce across the 4 quads holding this row
        n2 += __shfl_xor(n2, 16, WAVE);
        n2 += __shfl_xor(n2, 32, WAVE);
        float nrm = fmaxf(sqrtf(n2), 1e-6f);
        float x0c = fmaxf(sqc * x0, 1.f + 1e-7f);
        float f = (acoshf(x0c) / sqc) / nrm;
        #pragma unroll
        for (int kk = 0; kk < 4; ++kk) {
            bf16x8 fr;
            #pragma unroll
            for (int j = 0; j < 8; ++j) fr[j] = (short)f2b(vals[kk][j] * f);
            a[kk] = fr;
            if (row < M)
                *(bf16x8*)&xtan_bf[(size_t)row * 128 + kk * 32 + quad * 8] = fr;
        }
    } else {
        #pragma unroll
        for (int kk = 0; kk < 4; ++kk)
            a[kk] = *(const bf16x8*)&xtan_bf[(size_t)rowc * 128 + kk * 32 + quad * 8];
    }

    // ---- GEMM 1 ----
    f32x4 acc[8];
    #pragma unroll
    for (int nt = 0; nt < 8; ++nt) acc[nt] = (f32x4){0.f, 0.f, 0.f, 0.f};
    #pragma unroll
    for (int kk = 0; kk < 4; ++kk) {
        #pragma unroll
        for (int nt = 0; nt < 8; ++nt) {
            bf16x8 b = *(const bf16x8*)&LW[(size_t)(nt * 16 + l16) * 128 + kk * 32 + quad * 8];
            acc[nt] = __builtin_amdgcn_mfma_f32_16x16x32_bf16(a[kk], b, acc[nt], 0, 0, 0);
        }
    }
    #pragma unroll
    for (int nt = 0; nt < 8; ++nt) {
        float bv = bias[nt * 16 + l16];
        #pragma unroll
        for (int r = 0; r < 4; ++r) {
            int lrow = wave * 16 + quad * 4 + r;
            xs[lrow * 136 + nt * 16 + l16] = f2b(acc[nt][r] + bv);
        }
    }
    __syncthreads();

    bf16x8 a2[4];
    int lrowr = wave * 16 + l16;
    #pragma unroll
    for (int kk = 0; kk < 4; ++kk) {
        a2[kk] = *(const bf16x8*)&xs[lrowr * 136 + kk * 32 + quad * 8];
        if (row < M)
            *(bf16x8*)&xlin[(size_t)row * 128 + kk * 32 + quad * 8] = a2[kk];
    }

    // ---- GEMM 2 ----
    f32x4 acc2[8];
    #pragma unroll
    for (int nt = 0; nt < 8; ++nt) acc2[nt] = (f32x4){0.f, 0.f, 0.f, 0.f};
    #pragma unroll
    for (int kk = 0; kk < 4; ++kk) {
        #pragma unroll
        for (int nt = 0; nt < 8; ++nt) {
            bf16x8 b = *(const bf16x8*)&WT[(size_t)(nt * 16 + l16) * 128 + kk * 32 + quad * 8];
            acc2[nt] = __builtin_amdgcn_mfma_f32_16x16x32_bf16(a2[kk], b, acc2[nt], 0, 0, 0);
        }
    }
    #pragma unroll
    for (int nt = 0; nt < 8; ++nt) {
        #pragma unroll
        for (int r = 0; r < 4; ++r) {
            int rr = m0w + quad * 4 + r;
            if (rr < M) acat[(size_t)rr * 128 + nt * 16 + l16] = f2b(acc2[nt][r]);
        }
    }
}

// ---------------------------------------------------------------------------
// k_B: fused edge phase + LN + expmap (+ analytic logmap to next layer).
// One wave per node. Scores: 4 edges in parallel (one per 16-lane quad).
// Gather: 2 edges per iteration (32-lane halves, ushort4 loads).
//   if last: write out row (129-stride fp32)
//   else:    xtan_bf[node] <- logmap_{c_next}(expmap_{c}(y))  (bf16)
// ---------------------------------------------------------------------------
__global__ __launch_bounds__(256) void k_B(
    const int* __restrict__ rs, const int2* __restrict__ epack,
    const unsigned short* __restrict__ acat, const unsigned short* __restrict__ xlin,
    unsigned short* __restrict__ xtan_bf, const float* __restrict__ ae,
    const float* __restrict__ emb, const float* __restrict__ w2,
    const float* __restrict__ b2, const float* __restrict__ sib,
    const float* __restrict__ g, const float* __restrict__ b,
    const float* __restrict__ curv, const float* __restrict__ curv_n,
    int last, float* __restrict__ out, int N)
{
    int wid = (blockIdx.x * blockDim.x + threadIdx.x) >> 6;
    int lane = threadIdx.x & 63;
    if (wid >= N) return;
    int quad = lane >> 4;
    int l16  = lane & 15;
    int half = lane >> 5;
    int li   = lane & 31;
    float c = fminf(fmaxf(curv[0], 0.1f), 10.f);
    float sqc = sqrtf(c);
    int p0 = rs[wid], p1 = rs[wid + 1];

    ushort4 adu = *(const ushort4*)&acat[(size_t)wid * 128 + 4 * l16];
    float4 w2v = *(const float4*)&w2[4 * l16];
    float b2v = b2[0], sibv = sib[0];

    float4 acc = make_float4(0.f, 0.f, 0.f, 0.f);
    float S = 0.f;

    for (int pc = p0; pc < p1; pc += 4) {
        // ---- score: edge pc+quad (one per quad) ----
        int pe = pc + quad;
        bool valid = pe < p1;
        int2 r = epack[valid ? pe : p0];
        int srcq = r.x & 0xFFFFFF;
        int tq = ((unsigned)r.x) >> 24;
        float wq = __int_as_float(r.y);
        ushort4 asu = *(const ushort4*)&acat[(size_t)srcq * 128 + 64 + 4 * l16];
        float4 av = *(const float4*)&ae[tq * 64 + 4 * l16];
        float d = silu(b2f(adu.x) + b2f(asu.x) + av.x) * w2v.x
                + silu(b2f(adu.y) + b2f(asu.y) + av.y) * w2v.y
                + silu(b2f(adu.z) + b2f(asu.z) + av.z) * w2v.z
                + silu(b2f(adu.w) + b2f(asu.w) + av.w) * w2v.w;
        #pragma unroll
        for (int m = 1; m < 16; m <<= 1) d += __shfl_xor(d, m, WAVE);
        float s = d + b2v + logf(fmaxf(wq, 1e-6f));
        if (tq == 1) s += sibv;
        float exv = valid ? expf(s) : 0.f;
        // broadcast the 4 quad ex values to all lanes
        float e0 = __shfl(exv, l16, WAVE);
        float e1 = __shfl(exv, 16 + l16, WAVE);
        float e2 = __shfl(exv, 32 + l16, WAVE);
        float e3 = __shfl(exv, 48 + l16, WAVE);
        S += e0 + e1 + e2 + e3;

        // ---- gather: edges pc+2j+half, j=0,1 ----
        #pragma unroll
        for (int j = 0; j < 2; ++j) {
            int pg = pc + 2 * j + half;
            int2 rg = epack[pg < p1 ? pg : p0];
            int src = rg.x & 0xFFFFFF;
            int t = ((unsigned)rg.x) >> 24;
            float w = __int_as_float(rg.y);
            float exg = j == 0 ? (half ? e1 : e0) : (half ? e3 : e2);
            float cf = exg * w;              // 0 for invalid edges
            ushort4 xu = *(const ushort4*)&xlin[(size_t)src * 128 + 4 * li];
            float4 em = *(const float4*)&emb[t * 128 + 4 * li];
            acc.x += (b2f(xu.x) + em.x) * cf;
            acc.y += (b2f(xu.y) + em.y) * cf;
            acc.z += (b2f(xu.z) + em.z) * cf;
            acc.w += (b2f(xu.w) + em.w) * cf;
        }
    }
    // merge halves
    acc.x += __shfl_xor(acc.x, 32, WAVE);
    acc.y += __shfl_xor(acc.y, 32, WAVE);
    acc.z += __shfl_xor(acc.z, 32, WAVE);
    acc.w += __shfl_xor(acc.w, 32, WAVE);

    float inv = 1.f / (S + 1e-16f);
    ushort4 xtu = *(const ushort4*)&xtan_bf[(size_t)wid * 128 + 4 * li];
    float4 y;
    y.x = b2f(xtu.x) + acc.x * inv;
    y.y = b2f(xtu.y) + acc.y * inv;
    y.z = b2f(xtu.z) + acc.z * inv;
    y.w = b2f(xtu.w) + acc.w * inv;

    // LayerNorm (reduce within 32-lane half; halves identical)
    float sum = y.x + y.y + y.z + y.w;
    float sq = y.x * y.x + y.y * y.y + y.z * y.z + y.w * y.w;
    #pragma unroll
    for (int m = 1; m < 32; m <<= 1) {
        sum += __shfl_xor(sum, m, WAVE);
        sq  += __shfl_xor(sq, m, WAVE);
    }
    float mu = sum * (1.f / 128.f);
    float var = sq * (1.f / 128.f) - mu * mu;
    float invs = rsqrtf(var + 1e-5f);
    float4 gg = *(const float4*)&g[4 * li];
    float4 bb = *(const float4*)&b[4 * li];
    y.x = (y.x - mu) * invs * gg.x + bb.x;
    y.y = (y.y - mu) * invs * gg.y + bb.y;
    y.z = (y.z - mu) * invs * gg.z + bb.z;
    y.w = (y.w - mu) * invs * gg.w + bb.w;

    // exp map
    float nrm2 = y.x * y.x + y.y * y.y + y.z * y.z + y.w * y.w;
    #pragma unroll
    for (int m = 1; m < 32; m <<= 1) nrm2 += __shfl_xor(nrm2, m, WAVE);
    float nrm = fmaxf(sqrtf(nrm2), 1e-6f);
    float th = sqc * nrm;
    float sc = sinhf(th) / (sqc * nrm);

    if (last) {
        float* o = out + (size_t)wid * 129;
        if (lane == 0) o[0] = coshf(th) / sqc;
        if (half == 0) {
            o[1 + 4 * li] = y.x * sc;
            o[2 + 4 * li] = y.y * sc;
        } else {
            o[3 + 4 * li] = y.z * sc;
            o[4 + 4 * li] = y.w * sc;
        }
    } else {
        // analytic logmap with next layer's curvature (all scalar)
        float x0 = coshf(th) / sqc;
        float c2 = fminf(fmaxf(curv_n[0], 0.1f), 10.f);
        float sqc2 = sqrtf(c2);
        float x0c = fmaxf(sqc2 * x0, 1.f + 1e-7f);
        float dist = acoshf(x0c) / sqc2;
        float nsp = fmaxf(sinhf(th) / sqc, 1e-6f);   // norm of spatial part
        float sf = sc * (dist / nsp);
        if (half == 0) {
            ushort4 o4;
            o4.x = f2b(y.x * sf);
            o4.y = f2b(y.y * sf);
            o4.z = f2b(y.z * sf);
            o4.w = f2b(y.w * sf);
            *(ushort4*)&xtan_bf[(size_t)wid * 128 + 4 * li] = o4;
        }
    }
}

// ---------------------------------------------------------------------------
extern "C" void kernel_launch(void* const* d_in, const int* in_sizes, int n_in,
                              void* d_out, int out_size, void* d_ws, size_t ws_size,
                              hipStream_t stream) {
    const float* x_hyp = (const float*)d_in[0];
    const int*   ei    = (const int*)d_in[1];
    const int*   et    = (const int*)d_in[2];
    const float* ew    = (const float*)d_in[3];
    const float* lin_w = (const float*)d_in[4];
    const float* lin_b = (const float*)d_in[5];
    const float* ln_g  = (const float*)d_in[6];
    const float* ln_b  = (const float*)d_in[7];
    const float* emb   = (const float*)d_in[8];
    const float* w1    = (const float*)d_in[9];
    const float* b1    = (const float*)d_in[10];
    const float* w2    = (const float*)d_in[11];
    const float* b2    = (const float*)d_in[12];
    const float* sib   = (const float*)d_in[13];
    const float* curv  = (const float*)d_in[14];
    float* out = (float*)d_out;
    float* ws  = (float*)d_ws;

    const int N = in_sizes[0] / 129;
    const int E = in_sizes[2];
    const int L = in_sizes[4] / (128 * 128);
    const int NB = (N + 255) / 256;

    unsigned short* xtan_bf = (unsigned short*)ws;                // N*128
    unsigned short* xlin_bf = xtan_bf + (size_t)N * 128;          // N*128
    unsigned short* acat_bf = xlin_bf + (size_t)N * 128;          // N*128
    int2* epack = (int2*)(acat_bf + (size_t)N * 128);             // E
    unsigned short* lw_bf = (unsigned short*)(epack + E);         // L*16384
    unsigned short* Wt_bf = lw_bf + (size_t)L * 16384;            // L*16384
    float* ae   = (float*)(Wt_bf + (size_t)L * 16384);            // L*256
    int* deg    = (int*)(ae + (size_t)L * 256);                   // N (cursor)
    int* rs     = deg + N;                                        // N+1
    int* btot   = rs + N + 1;                                     // 256

    // ---- CSR build (once; edges static across layers) ----
    hipMemsetAsync(deg, 0, (size_t)N * sizeof(int), stream);
    k_hist<<<(E + 255) / 256, 256, 0, stream>>>(ei, deg, E);
    k_scan1<<<NB, 256, 0, stream>>>(deg, rs, btot, N);
    k_scan2<<<1, 256, 0, stream>>>(btot, NB);
    k_scan3<<<NB, 256, 0, stream>>>(rs, btot, deg /*cursor*/, N, E);
    k_scatter<<<(E + 255) / 256, 256, 0, stream>>>(ei, et, ew, deg /*cursor*/,
                                                   epack, E);
    // ---- all-layer weight prep ----
    k_prep<<<L * 129, 256, 0, stream>>>(lin_w, w1, b1, emb, lw_bf, Wt_bf, ae);

    for (int l = 0; l < L; ++l) {
        k_A<<<(N + 63) / 64, 256, 0, stream>>>(
            x_hyp, xtan_bf, l == 0 ? 1 : 0,
            lw_bf + (size_t)l * 16384, Wt_bf + (size_t)l * 16384,
            lin_b + (size_t)l * 128, xlin_bf, acat_bf, curv + l, N);
        k_B<<<(N + 3) / 4, 256, 0, stream>>>(
            rs, epack, acat_bf, xlin_bf, xtan_bf,
            ae + (size_t)l * 256, emb + (size_t)l * 512,
            w2 + (size_t)l * 64, b2 + l, sib + l,
            ln_g + (size_t)l * 128, ln_b + (size_t)l * 128,
            curv + l, curv + (l + 1 < L ? l + 1 : l),
            l == L - 1 ? 1 : 0, out, N);
    }
}

// Round 7
// 290.152 us; speedup vs baseline: 2.2296x; 1.0929x over previous
//
#include <hip/hip_runtime.h>
#include <hip/hip_bf16.h>
#include <math.h>

#define WAVE 64

typedef __attribute__((ext_vector_type(8))) short bf16x8;
typedef __attribute__((ext_vector_type(4))) float f32x4;

__device__ __forceinline__ float wave_reduce_sum(float v) {
    #pragma unroll
    for (int off = 32; off > 0; off >>= 1) v += __shfl_xor(v, off, WAVE);
    return v;
}

// bf16 <-> f32 helpers (bit-level, RNE on pack)
__device__ __forceinline__ unsigned short f2b(float f) {
    unsigned u = __float_as_uint(f);
    unsigned r = (u + 0x7FFFu + ((u >> 16) & 1u)) >> 16;
    return (unsigned short)r;
}
__device__ __forceinline__ float b2f(unsigned short u) {
    return __uint_as_float(((unsigned)u) << 16);
}

// fast transcendentals (v_exp/v_log/v_rcp/v_rsq/v_sqrt; err ~1e-6 rel,
// far below bf16 noise in this pipeline)
__device__ __forceinline__ float frcp(float x)  { return __builtin_amdgcn_rcpf(x); }
__device__ __forceinline__ float frsq(float x)  { return __builtin_amdgcn_rsqf(x); }
__device__ __forceinline__ float fsqrtf(float x){ return __builtin_amdgcn_sqrtf(x); }
__device__ __forceinline__ float silu(float x)  { return x * frcp(1.f + __expf(-x)); }
__device__ __forceinline__ float facosh(float x){ return __logf(x + fsqrtf(x * x - 1.f)); }

// ---------------------------------------------------------------------------
// Prep (all layers, one dispatch): lw_bf = bf16(lin_w); Wt_bf from w1;
// ae = b1 + emb @ w1[256:].  grid = L*129 blocks x 256.
// ---------------------------------------------------------------------------
__global__ void k_prep(const float* __restrict__ lin_w, const float* __restrict__ w1,
                       const float* __restrict__ b1, const float* __restrict__ emb,
                       unsigned short* __restrict__ lw_bf,
                       unsigned short* __restrict__ Wt_bf, float* __restrict__ ae) {
    int l = blockIdx.x / 129, bx = blockIdx.x % 129, tid = threadIdx.x;
    const float* lwl = lin_w + (size_t)l * 16384;
    const float* w1l = w1 + (size_t)l * 384 * 64;
    if (bx < 64) {
        int idx = bx * 256 + tid;
        lw_bf[l * 16384 + idx] = f2b(lwl[idx]);
    } else if (bx < 128) {
        int idx = (bx - 64) * 256 + tid;
        int o = idx >> 7, i = idx & 127;
        float v = (o < 64) ? w1l[i * 64 + o] : w1l[(128 + i) * 64 + (o - 64)];
        Wt_bf[l * 16384 + idx] = f2b(v);
    } else {
        int t = tid >> 6, h = tid & 63;
        float s = b1[l * 64 + h];
        #pragma unroll 8
        for (int i = 0; i < 128; ++i)
            s += emb[l * 512 + t * 128 + i] * w1l[(256 + i) * 64 + h];
        ae[l * 256 + tid] = s;
    }
}

// ---------------------------------------------------------------------------
// CSR build
// ---------------------------------------------------------------------------
__global__ void k_hist(const int* __restrict__ ei, int* __restrict__ deg, int E) {
    int e = blockIdx.x * 256 + threadIdx.x;
    if (e < E) atomicAdd(&deg[ei[E + e]], 1);
}

__global__ void k_scan1(const int* __restrict__ deg, int* __restrict__ rs,
                        int* __restrict__ btot, int N) {
    __shared__ int wsum[4];
    int i = blockIdx.x * 256 + threadIdx.x;
    int v = (i < N) ? deg[i] : 0;
    int lane = threadIdx.x & 63, w = threadIdx.x >> 6;
    int x = v;
    #pragma unroll
    for (int off = 1; off < 64; off <<= 1) {
        int t = __shfl_up(x, off, 64);
        if (lane >= off) x += t;
    }
    if (lane == 63) wsum[w] = x;
    __syncthreads();
    int woff = 0;
    for (int j = 0; j < w; ++j) woff += wsum[j];
    int incl = woff + x;
    if (i < N) rs[i] = incl - v;
    if (threadIdx.x == 255) btot[blockIdx.x] = incl;
}

__global__ void k_scan2(int* __restrict__ btot, int nb) {
    __shared__ int wsum[4];
    int i = threadIdx.x;
    int v = (i < nb) ? btot[i] : 0;
    int lane = i & 63, w = i >> 6;
    int x = v;
    #pragma unroll
    for (int off = 1; off < 64; off <<= 1) {
        int t = __shfl_up(x, off, 64);
        if (lane >= off) x += t;
    }
    if (lane == 63) wsum[w] = x;
    __syncthreads();
    int woff = 0;
    for (int j = 0; j < w; ++j) woff += wsum[j];
    int incl = woff + x;
    __syncthreads();
    if (i < nb) btot[i] = incl - v;
}

__global__ void k_scan3(int* __restrict__ rs, const int* __restrict__ btot,
                        int* __restrict__ cursor, int N, int E) {
    int i = blockIdx.x * 256 + threadIdx.x;
    if (i < N) {
        int v = rs[i] + btot[blockIdx.x];
        rs[i] = v;
        cursor[i] = v;
    }
    if (i == 0) rs[N] = E;
}

__global__ void k_scatter(const int* __restrict__ ei, const int* __restrict__ et,
                          const float* __restrict__ ew, int* __restrict__ cursor,
                          int2* __restrict__ epack, int E) {
    int e = blockIdx.x * 256 + threadIdx.x;
    if (e >= E) return;
    int dst = ei[E + e];
    int pos = atomicAdd(&cursor[dst], 1);
    int2 r;
    r.x = ei[e] | (et[e] << 24);
    r.y = __float_as_int(ew[e]);
    epack[pos] = r;
}

// ---------------------------------------------------------------------------
// k_A: [optional logmap] + fused double GEMM (MFMA bf16).
// ---------------------------------------------------------------------------
__global__ __launch_bounds__(256) void k_A(
    const float* __restrict__ xh, unsigned short* __restrict__ xtan_bf,
    int from_hyp,
    const unsigned short* __restrict__ LW, const unsigned short* __restrict__ WT,
    const float* __restrict__ bias,
    unsigned short* __restrict__ xlin, unsigned short* __restrict__ acat,
    const float* __restrict__ curv, int M)
{
    __shared__ unsigned short xs[64 * 136];
    int wave = threadIdx.x >> 6;
    int lane = threadIdx.x & 63;
    int quad = lane >> 4;
    int l16  = lane & 15;
    int m0w = blockIdx.x * 64 + wave * 16;
    int row = m0w + l16;
    int rowc = row < M ? row : M - 1;

    bf16x8 a[4];
    if (from_hyp) {
        float c = fminf(fmaxf(curv[0], 0.1f), 10.f);
        float sqc = fsqrtf(c);
        const float* xr = xh + (size_t)rowc * 129;
        float x0 = xr[0];
        float vals[4][8];
        float n2 = 0.f;
        #pragma unroll
        for (int kk = 0; kk < 4; ++kk)
            #pragma unroll
            for (int j = 0; j < 8; ++j) {
                float v = xr[1 + kk * 32 + quad * 8 + j];
                vals[kk][j] = v;
                n2 += v * v;
            }
        n2 += __shfl_xor(n2, 16, WAVE);
        n2 += __shfl_xor(n2, 32, WAVE);
        float nrm = fmaxf(fsqrtf(n2), 1e-6f);
        float x0c = fmaxf(sqc * x0, 1.f + 1e-7f);
        float f = facosh(x0c) * frcp(sqc) * frcp(nrm);
        #pragma unroll
        for (int kk = 0; kk < 4; ++kk) {
            bf16x8 fr;
            #pragma unroll
            for (int j = 0; j < 8; ++j) fr[j] = (short)f2b(vals[kk][j] * f);
            a[kk] = fr;
            if (row < M)
                *(bf16x8*)&xtan_bf[(size_t)row * 128 + kk * 32 + quad * 8] = fr;
        }
    } else {
        #pragma unroll
        for (int kk = 0; kk < 4; ++kk)
            a[kk] = *(const bf16x8*)&xtan_bf[(size_t)rowc * 128 + kk * 32 + quad * 8];
    }

    // ---- GEMM 1 ----
    f32x4 acc[8];
    #pragma unroll
    for (int nt = 0; nt < 8; ++nt) acc[nt] = (f32x4){0.f, 0.f, 0.f, 0.f};
    #pragma unroll
    for (int kk = 0; kk < 4; ++kk) {
        #pragma unroll
        for (int nt = 0; nt < 8; ++nt) {
            bf16x8 b = *(const bf16x8*)&LW[(size_t)(nt * 16 + l16) * 128 + kk * 32 + quad * 8];
            acc[nt] = __builtin_amdgcn_mfma_f32_16x16x32_bf16(a[kk], b, acc[nt], 0, 0, 0);
        }
    }
    #pragma unroll
    for (int nt = 0; nt < 8; ++nt) {
        float bv = bias[nt * 16 + l16];
        #pragma unroll
        for (int r = 0; r < 4; ++r) {
            int lrow = wave * 16 + quad * 4 + r;
            xs[lrow * 136 + nt * 16 + l16] = f2b(acc[nt][r] + bv);
        }
    }
    __syncthreads();

    bf16x8 a2[4];
    int lrowr = wave * 16 + l16;
    #pragma unroll
    for (int kk = 0; kk < 4; ++kk) {
        a2[kk] = *(const bf16x8*)&xs[lrowr * 136 + kk * 32 + quad * 8];
        if (row < M)
            *(bf16x8*)&xlin[(size_t)row * 128 + kk * 32 + quad * 8] = a2[kk];
    }

    // ---- GEMM 2 ----
    f32x4 acc2[8];
    #pragma unroll
    for (int nt = 0; nt < 8; ++nt) acc2[nt] = (f32x4){0.f, 0.f, 0.f, 0.f};
    #pragma unroll
    for (int kk = 0; kk < 4; ++kk) {
        #pragma unroll
        for (int nt = 0; nt < 8; ++nt) {
            bf16x8 b = *(const bf16x8*)&WT[(size_t)(nt * 16 + l16) * 128 + kk * 32 + quad * 8];
            acc2[nt] = __builtin_amdgcn_mfma_f32_16x16x32_bf16(a2[kk], b, acc2[nt], 0, 0, 0);
        }
    }
    #pragma unroll
    for (int nt = 0; nt < 8; ++nt) {
        #pragma unroll
        for (int r = 0; r < 4; ++r) {
            int rr = m0w + quad * 4 + r;
            if (rr < M) acat[(size_t)rr * 128 + nt * 16 + l16] = f2b(acc2[nt][r]);
        }
    }
}

// ---------------------------------------------------------------------------
// k_B: fused edge phase + LN + expmap (+ analytic logmap to next layer).
// One wave per node, 4 edges per iteration: each 16-lane quad scores AND
// gathers its own edge (8 dims/lane, bf16x8 loads). Cross-quad reduce once
// per node. Fast transcendentals throughout.
// ---------------------------------------------------------------------------
__global__ __launch_bounds__(256) void k_B(
    const int* __restrict__ rs, const int2* __restrict__ epack,
    const unsigned short* __restrict__ acat, const unsigned short* __restrict__ xlin,
    unsigned short* __restrict__ xtan_bf, const float* __restrict__ ae,
    const float* __restrict__ emb, const float* __restrict__ w2,
    const float* __restrict__ b2, const float* __restrict__ sib,
    const float* __restrict__ g, const float* __restrict__ b,
    const float* __restrict__ curv, const float* __restrict__ curv_n,
    int last, float* __restrict__ out, int N)
{
    int wid = (blockIdx.x * blockDim.x + threadIdx.x) >> 6;
    int lane = threadIdx.x & 63;
    if (wid >= N) return;
    int quad = lane >> 4;
    int l16  = lane & 15;
    float c = fminf(fmaxf(curv[0], 0.1f), 10.f);
    float sqc = fsqrtf(c);
    float rsqc = frcp(sqc);
    int p0 = rs[wid], p1 = rs[wid + 1];

    // loop-invariant: dst half of the attention pre-activation (dims 4*l16..)
    ushort4 adu = *(const ushort4*)&acat[(size_t)wid * 128 + 4 * l16];
    float ad0 = b2f(adu.x), ad1 = b2f(adu.y), ad2 = b2f(adu.z), ad3 = b2f(adu.w);
    float4 w2v = *(const float4*)&w2[4 * l16];
    float b2v = b2[0], sibv = sib[0];

    float acc[8];
    #pragma unroll
    for (int j = 0; j < 8; ++j) acc[j] = 0.f;
    float S = 0.f;

    for (int pc = p0; pc < p1; pc += 4) {
        int pe = pc + quad;
        bool valid = pe < p1;
        int2 r = epack[valid ? pe : p0];
        int src = r.x & 0xFFFFFF;
        int t = ((unsigned)r.x) >> 24;
        float w = __int_as_float(r.y);

        // ---- score (16 lanes, 4 dims each) ----
        ushort4 asu = *(const ushort4*)&acat[(size_t)src * 128 + 64 + 4 * l16];
        float4 av = *(const float4*)&ae[t * 64 + 4 * l16];
        float d = silu(ad0 + b2f(asu.x) + av.x) * w2v.x
                + silu(ad1 + b2f(asu.y) + av.y) * w2v.y
                + silu(ad2 + b2f(asu.z) + av.z) * w2v.z
                + silu(ad3 + b2f(asu.w) + av.w) * w2v.w;
        #pragma unroll
        for (int m = 1; m < 16; m <<= 1) d += __shfl_xor(d, m, WAVE);
        float s = d + b2v + __logf(fmaxf(w, 1e-6f));
        if (t == 1) s += sibv;
        float exv = valid ? __expf(s) : 0.f;
        S += exv;

        // ---- gather (same edge, 8 dims/lane) ----
        float cf = exv * w;
        bf16x8 xu = *(const bf16x8*)&xlin[(size_t)src * 128 + 8 * l16];
        float4 em0 = *(const float4*)&emb[t * 128 + 8 * l16];
        float4 em1 = *(const float4*)&emb[t * 128 + 8 * l16 + 4];
        acc[0] += (b2f((unsigned short)xu[0]) + em0.x) * cf;
        acc[1] += (b2f((unsigned short)xu[1]) + em0.y) * cf;
        acc[2] += (b2f((unsigned short)xu[2]) + em0.z) * cf;
        acc[3] += (b2f((unsigned short)xu[3]) + em0.w) * cf;
        acc[4] += (b2f((unsigned short)xu[4]) + em1.x) * cf;
        acc[5] += (b2f((unsigned short)xu[5]) + em1.y) * cf;
        acc[6] += (b2f((unsigned short)xu[6]) + em1.z) * cf;
        acc[7] += (b2f((unsigned short)xu[7]) + em1.w) * cf;
    }
    // cross-quad reduce: every lane gets the node totals for dims 8*l16..+7
    #pragma unroll
    for (int j = 0; j < 8; ++j) {
        acc[j] += __shfl_xor(acc[j], 16, WAVE);
        acc[j] += __shfl_xor(acc[j], 32, WAVE);
    }
    S += __shfl_xor(S, 16, WAVE);
    S += __shfl_xor(S, 32, WAVE);

    float inv = frcp(S + 1e-16f);
    bf16x8 xtu = *(const bf16x8*)&xtan_bf[(size_t)wid * 128 + 8 * l16];
    float y[8];
    #pragma unroll
    for (int j = 0; j < 8; ++j)
        y[j] = b2f((unsigned short)xtu[j]) + acc[j] * inv;

    // LayerNorm (16 lanes x 8 dims cover all 128; quads hold identical copies)
    float sum = 0.f, sq = 0.f;
    #pragma unroll
    for (int j = 0; j < 8; ++j) { sum += y[j]; sq += y[j] * y[j]; }
    #pragma unroll
    for (int m = 1; m < 16; m <<= 1) {
        sum += __shfl_xor(sum, m, WAVE);
        sq  += __shfl_xor(sq, m, WAVE);
    }
    float mu = sum * (1.f / 128.f);
    float var = sq * (1.f / 128.f) - mu * mu;
    float invs = frsq(var + 1e-5f);
    float4 g0 = *(const float4*)&g[8 * l16];
    float4 g1 = *(const float4*)&g[8 * l16 + 4];
    float4 bb0 = *(const float4*)&b[8 * l16];
    float4 bb1 = *(const float4*)&b[8 * l16 + 4];
    y[0] = (y[0] - mu) * invs * g0.x + bb0.x;
    y[1] = (y[1] - mu) * invs * g0.y + bb0.y;
    y[2] = (y[2] - mu) * invs * g0.z + bb0.z;
    y[3] = (y[3] - mu) * invs * g0.w + bb0.w;
    y[4] = (y[4] - mu) * invs * g1.x + bb1.x;
    y[5] = (y[5] - mu) * invs * g1.y + bb1.y;
    y[6] = (y[6] - mu) * invs * g1.z + bb1.z;
    y[7] = (y[7] - mu) * invs * g1.w + bb1.w;

    // exp map (fast cosh/sinh from one exp)
    float nrm2 = 0.f;
    #pragma unroll
    for (int j = 0; j < 8; ++j) nrm2 += y[j] * y[j];
    #pragma unroll
    for (int m = 1; m < 16; m <<= 1) nrm2 += __shfl_xor(nrm2, m, WAVE);
    float nrm = fmaxf(fsqrtf(nrm2), 1e-6f);
    float th = sqc * nrm;
    float e = __expf(th);
    float ei = frcp(e);
    float ch = 0.5f * (e + ei);
    float sh = 0.5f * (e - ei);
    float sc = sh * frcp(sqc * nrm);

    if (last) {
        float* o = out + (size_t)wid * 129;
        if (lane == 0) o[0] = ch * rsqc;
        if (lane < 16) {
            #pragma unroll
            for (int j = 0; j < 8; ++j) o[1 + 8 * l16 + j] = y[j] * sc;
        }
    } else {
        // analytic logmap with next layer's curvature
        float x0 = ch * rsqc;
        float c2 = fminf(fmaxf(curv_n[0], 0.1f), 10.f);
        float sqc2 = fsqrtf(c2);
        float x0c = fmaxf(sqc2 * x0, 1.f + 1e-7f);
        float dist = facosh(x0c) * frcp(sqc2);
        float nsp = fmaxf(sh * rsqc, 1e-6f);   // norm of spatial part
        float sf = sc * dist * frcp(nsp);
        if (lane < 16) {
            bf16x8 o8;
            #pragma unroll
            for (int j = 0; j < 8; ++j) o8[j] = (short)f2b(y[j] * sf);
            *(bf16x8*)&xtan_bf[(size_t)wid * 128 + 8 * l16] = o8;
        }
    }
}

// ---------------------------------------------------------------------------
extern "C" void kernel_launch(void* const* d_in, const int* in_sizes, int n_in,
                              void* d_out, int out_size, void* d_ws, size_t ws_size,
                              hipStream_t stream) {
    const float* x_hyp = (const float*)d_in[0];
    const int*   ei    = (const int*)d_in[1];
    const int*   et    = (const int*)d_in[2];
    const float* ew    = (const float*)d_in[3];
    const float* lin_w = (const float*)d_in[4];
    const float* lin_b = (const float*)d_in[5];
    const float* ln_g  = (const float*)d_in[6];
    const float* ln_b  = (const float*)d_in[7];
    const float* emb   = (const float*)d_in[8];
    const float* w1    = (const float*)d_in[9];
    const float* b1    = (const float*)d_in[10];
    const float* w2    = (const float*)d_in[11];
    const float* b2    = (const float*)d_in[12];
    const float* sib   = (const float*)d_in[13];
    const float* curv  = (const float*)d_in[14];
    float* out = (float*)d_out;
    float* ws  = (float*)d_ws;

    const int N = in_sizes[0] / 129;
    const int E = in_sizes[2];
    const int L = in_sizes[4] / (128 * 128);
    const int NB = (N + 255) / 256;

    unsigned short* xtan_bf = (unsigned short*)ws;                // N*128
    unsigned short* xlin_bf = xtan_bf + (size_t)N * 128;          // N*128
    unsigned short* acat_bf = xlin_bf + (size_t)N * 128;          // N*128
    int2* epack = (int2*)(acat_bf + (size_t)N * 128);             // E
    unsigned short* lw_bf = (unsigned short*)(epack + E);         // L*16384
    unsigned short* Wt_bf = lw_bf + (size_t)L * 16384;            // L*16384
    float* ae   = (float*)(Wt_bf + (size_t)L * 16384);            // L*256
    int* deg    = (int*)(ae + (size_t)L * 256);                   // N (cursor)
    int* rs     = deg + N;                                        // N+1
    int* btot   = rs + N + 1;                                     // 256

    // ---- CSR build (once; edges static across layers) ----
    hipMemsetAsync(deg, 0, (size_t)N * sizeof(int), stream);
    k_hist<<<(E + 255) / 256, 256, 0, stream>>>(ei, deg, E);
    k_scan1<<<NB, 256, 0, stream>>>(deg, rs, btot, N);
    k_scan2<<<1, 256, 0, stream>>>(btot, NB);
    k_scan3<<<NB, 256, 0, stream>>>(rs, btot, deg /*cursor*/, N, E);
    k_scatter<<<(E + 255) / 256, 256, 0, stream>>>(ei, et, ew, deg /*cursor*/,
                                                   epack, E);
    // ---- all-layer weight prep ----
    k_prep<<<L * 129, 256, 0, stream>>>(lin_w, w1, b1, emb, lw_bf, Wt_bf, ae);

    for (int l = 0; l < L; ++l) {
        k_A<<<(N + 63) / 64, 256, 0, stream>>>(
            x_hyp, xtan_bf, l == 0 ? 1 : 0,
            lw_bf + (size_t)l * 16384, Wt_bf + (size_t)l * 16384,
            lin_b + (size_t)l * 128, xlin_bf, acat_bf, curv + l, N);
        k_B<<<(N + 3) / 4, 256, 0, stream>>>(
            rs, epack, acat_bf, xlin_bf, xtan_bf,
            ae + (size_t)l * 256, emb + (size_t)l * 512,
            w2 + (size_t)l * 64, b2 + l, sib + l,
            ln_g + (size_t)l * 128, ln_b + (size_t)l * 128,
            curv + l, curv + (l + 1 < L ? l + 1 : l),
            l == L - 1 ? 1 : 0, out, N);
    }
}